// Round 7
// baseline (2118.176 us; speedup 1.0000x reference)
//
#include <hip/hip_runtime.h>
#include <cstdint>
#include <cstddef>

#define NB 8
#define NN 65536
#define NS (NN + 16)         // sorted-buffer row stride (row NN = zero sentinel)
#define GG 64
#define GG3 (GG*GG*GG)
#define NW (GG3/32)          // 8192 mask words per batch
#define NBLKC 1024           // 4 blocks/CU x 256 CU -> co-resident by construction
#define NTH (NBLKC*256)      // 262144 threads = (B*N)/2
#define EPSC 1e-3f

typedef __bf16 bf16x8 __attribute__((ext_vector_type(8)));
typedef float  f32x4  __attribute__((ext_vector_type(4)));

__device__ __forceinline__ unsigned short f2bf(float f) {
    unsigned u = __builtin_bit_cast(unsigned, f);
    unsigned r = (u + 0x7fffu + ((u >> 16) & 1u)) >> 16;
    return (unsigned short)r;
}
__device__ __forceinline__ unsigned pk2(float a, float b) {
    return (unsigned)f2bf(a) | ((unsigned)f2bf(b) << 16);
}
__device__ __forceinline__ float bf2f(unsigned short s) {
    return __builtin_bit_cast(float, (unsigned)s << 16);
}

__device__ __forceinline__ int site_rank2(const int2* __restrict__ mwb, int lin) {
    int2 mw = mwb[lin >> 5];
    uint32_t w = (uint32_t)mw.x;
    uint32_t bit = 1u << (lin & 31);
    if (!(w & bit)) return -1;
    return mw.y + __popc(w & (bit - 1u));
}

// ---------------------------------------------------------------------------
// device-scope generation barrier (graph-capturable; no cooperative API).
// bar[0..15]: striped arrival counters, bar[16]: root, bar[17]: generation.
// All zeroed by the pre-launch memset. Bounded spin = safety valve: a logic
// bug fails the test instead of hanging the container.
// ---------------------------------------------------------------------------
__device__ __forceinline__ void gbar(unsigned* bar) {
    __syncthreads();
    __threadfence();                       // release my block's writes (device scope)
    if (threadIdx.x == 0) {
        unsigned g = __hip_atomic_load(&bar[17], __ATOMIC_RELAXED, __HIP_MEMORY_SCOPE_AGENT);
        int s = blockIdx.x & 15;
        if (__hip_atomic_fetch_add(&bar[s], 1u, __ATOMIC_ACQ_REL, __HIP_MEMORY_SCOPE_AGENT)
                == (unsigned)(NBLKC / 16 - 1)) {
            if (__hip_atomic_fetch_add(&bar[16], 1u, __ATOMIC_ACQ_REL, __HIP_MEMORY_SCOPE_AGENT) == 15u) {
                #pragma unroll
                for (int i = 0; i < 17; i++)
                    __hip_atomic_store(&bar[i], 0u, __ATOMIC_RELAXED, __HIP_MEMORY_SCOPE_AGENT);
                __hip_atomic_fetch_add(&bar[17], 1u, __ATOMIC_RELEASE, __HIP_MEMORY_SCOPE_AGENT);
            }
        }
        unsigned spins = 0;
        while (__hip_atomic_load(&bar[17], __ATOMIC_ACQUIRE, __HIP_MEMORY_SCOPE_AGENT) == g) {
            __builtin_amdgcn_s_sleep(16);
            if (++spins > (1u << 22)) break;   // ~100ms safety valve
        }
    }
    __syncthreads();
    __threadfence();                       // acquire: invalidate stale L1/L2 lines
}

// per-channel scale/bias from striped stats (block-local, into LDS)
__device__ __forceinline__ void compute_sb(
    const float* __restrict__ stats, const int* __restrict__ nvv,
    const float* __restrict__ gamma, const float* __restrict__ beta,
    float* sbs, float* sums)
{
    int tid = threadIdx.x;
    if (tid < 32) {
        float v = 0.f;
        #pragma unroll
        for (int s = 0; s < 16; s++) v += stats[s * 32 + tid];
        sums[tid] = v;
    }
    __syncthreads();
    if (tid < 16) {
        float cnt = 0.f;
        #pragma unroll
        for (int b = 0; b < NB; b++) cnt += (float)nvv[b];
        float mean = sums[tid] / cnt;
        float var  = fmaxf(sums[16 + tid] / cnt - mean * mean, 0.f);
        float scv = gamma[tid] * rsqrtf(var + EPSC);
        sbs[tid]      = scv;
        sbs[16 + tid] = beta[tid] - mean * scv;
    }
    __syncthreads();
}

// ---------------------------------------------------------------------------
// conv phase: round-6 body (64-88 VGPR, spill-free) with XCD-locality
// mapping (batch = blockIdx&7); 4 tile-pairs per wave (512 waves/batch).
// ---------------------------------------------------------------------------
__device__ __forceinline__ void conv_phase(
    const unsigned short* __restrict__ sfeats,
    const int2* __restrict__ srow,
    const int* __restrict__ nvv,
    const int2* __restrict__ mwb,
    const unsigned short* __restrict__ wfrag,
    const float* __restrict__ nw,
    unsigned short* __restrict__ outbuf,
    float* __restrict__ stats,
    char* __restrict__ smraw)
{
    int lane = threadIdx.x & 63;
    int wv = threadIdx.x >> 6;
    int m = lane & 15, quad = lane >> 4;       // compute-phase layout
    int v = lane & 31, h = lane >> 5;          // rank-phase layout

    int b    = blockIdx.x & 7;                 // batch == XCD (heuristic)
    int widb = (blockIdx.x >> 3) * 4 + wv;     // wave-in-batch [0, 512)

    int   (*jj)[32][29] = (int(*)[32][29])smraw;
    float (*rrl)[32]    = (float(*)[32])(smraw + 14848);
    float (*red)[32]    = (float(*)[32])(smraw + 15360);
    float *lnw          = (float*)(smraw + 15872);

    if (threadIdx.x < 27) lnw[threadIdx.x] = nw[threadIdx.x];

    bf16x8 bfr[14];
    #pragma unroll
    for (int i = 0; i < 14; i++)
        bfr[i] = *(const bf16x8*)(wfrag + i * 512 + lane * 8);
    __syncthreads();

    float psum = 0.f, psq = 0.f;
    int coff = (quad & 1) << 3;

    // wave-uniform per-batch bases
    int cnt = nvv[b];
    const int2* mb = mwb + (size_t)b * NW;
    const unsigned short* fb = sfeats + (size_t)b * NS * 16;
    const int2* sr = srow + (size_t)b * NN;

    #pragma unroll 1
    for (int k = 0; k < 4; k++) {
        int r0 = (widb + k * 512) << 5;        // 32 ranks per pair-tile
        if (r0 >= cnt) continue;

        // ---- rank phase ----
        int Rv = r0 + v;
        bool vld = Rv < cnt;
        int lin = vld ? sr[Rv].x : 0;
        int x = lin >> 12, y = (lin >> 6) & 63, z = lin & 63;
        int zb = z & 31;
        float nc = 0.f;
        #pragma unroll
        for (int t = 0; t < 5; t++) {
            int c = 2 * t + h;
            bool cok = c < 9;
            int cc = cok ? c : 0;
            int dx = cc / 3 - 1, dy = cc % 3 - 1;
            int nx = x + dx, ny = y + dy;
            bool colok = cok & ((unsigned)nx < 64u) & ((unsigned)ny < 64u);
            int wdi = colok ? (((nx << 12) + (ny << 6) + z) >> 5) : 0;

            int2 mw = make_int2(0, 0);
            if (vld & colok) mw = mb[wdi];
            bool need2 = vld & colok & (((zb == 0) & (z > 0)) | ((zb == 31) & (z < 63)));
            int w2 = wdi + ((zb == 0) ? -1 : 1);
            int2 mw2 = make_int2(0, 0);
            if (need2) mw2 = mb[w2];

            #pragma unroll
            for (int dz = -1; dz <= 1; dz++) {
                int zz = z + dz;
                bool zok = (unsigned)zz < 64u;
                bool same = (dz == 0) | ((dz < 0) ? (zb != 0) : (zb != 31));
                int2 word = same ? mw : mw2;
                int bb = zz & 31;
                uint32_t wm = (uint32_t)word.x;
                bool hit = vld & colok & zok & ((wm >> bb) & 1u);
                int rnk = word.y + __popc(wm & ((1u << bb) - 1u));
                int off = cc * 3 + dz + 1;
                int jv = hit ? rnk : NN;
                if (cok) {
                    jj[wv][v][off] = jv;
                    nc += hit ? lnw[off] : 0.f;
                }
            }
        }
        nc += __shfl_xor(nc, 32, 64);
        if (lane < 32) rrl[wv][v] = 1.f / (1.f + fabsf(nc));

        // ---- compute phase: 28 gathers + 28 MFMAs (two independent chains) ----
        f32x4 acc0 = {0.f, 0.f, 0.f, 0.f};
        f32x4 acc1 = {0.f, 0.f, 0.f, 0.f};
        #pragma unroll
        for (int i = 0; i < 14; i++) {
            int off = 2 * i + (quad >> 1);
            int idx = off < 27 ? off : 28;
            int j0 = jj[wv][m][idx];      j0 = (off < 27) ? j0 : NN;
            int j1 = jj[wv][m + 16][idx]; j1 = (off < 27) ? j1 : NN;
            bf16x8 a0 = *(const bf16x8*)(fb + (size_t)j0 * 16 + coff);
            bf16x8 a1 = *(const bf16x8*)(fb + (size_t)j1 * 16 + coff);
            acc0 = __builtin_amdgcn_mfma_f32_16x16x32_bf16(a0, bfr[i], acc0, 0, 0, 0);
            acc1 = __builtin_amdgcn_mfma_f32_16x16x32_bf16(a1, bfr[i], acc1, 0, 0, 0);
        }

        // ---- epilogue ----
        #pragma unroll
        for (int hh = 0; hh < 2; hh++) {
            int rbase = r0 + (hh << 4);
            #pragma unroll
            for (int r4 = 0; r4 < 4; r4++) {
                int row = (quad << 2) + r4;
                float tval = (hh ? acc1[r4] : acc0[r4]) * rrl[wv][(hh << 4) + row];
                psum += tval; psq += tval * tval;
                int Rr = rbase + row;
                if (Rr < cnt)
                    outbuf[((size_t)b * NN + Rr) * 16 + m] = f2bf(tval);
            }
        }
    }

    // ---- BN partial stats ----
    psum += __shfl_xor(psum, 16, 64); psum += __shfl_xor(psum, 32, 64);
    psq  += __shfl_xor(psq, 16, 64);  psq  += __shfl_xor(psq, 32, 64);
    if (lane < 16) { red[wv][lane] = psum; red[wv][16 + lane] = psq; }
    __syncthreads();
    if (threadIdx.x < 32) {
        float vv = red[0][threadIdx.x] + red[1][threadIdx.x] +
                   red[2][threadIdx.x] + red[3][threadIdx.x];
        atomicAdd(&stats[(blockIdx.x & 15) * 32 + threadIdx.x], vv);
    }
}

// ---------------------------------------------------------------------------
// MEGA: all phases in one plain launch; 6 device barriers replace 7
// dispatch boundaries. Phase bodies = the verified round-6 kernels.
// ---------------------------------------------------------------------------
__global__ __launch_bounds__(256, 4) void mega_kernel(
    const float* __restrict__ feats,
    const int*   __restrict__ xyz,
    const int*   __restrict__ nvv,
    const float* __restrict__ w0, const float* __restrict__ w1,
    const float* __restrict__ nw0, const float* __restrict__ nw1,
    const float* __restrict__ gamma0, const float* __restrict__ beta0,
    const float* __restrict__ gamma1, const float* __restrict__ beta1,
    float* __restrict__ out,
    uint32_t* __restrict__ mask,
    float* __restrict__ stats1, float* __restrict__ stats2,
    unsigned* __restrict__ bar,
    int2* __restrict__ mwb,
    int2* __restrict__ srow,
    unsigned short* __restrict__ sfA,
    unsigned short* __restrict__ sfB,
    unsigned short* __restrict__ bufPre,
    unsigned short* __restrict__ wfr,
    int* __restrict__ rinv)
{
    __shared__ __align__(16) char smraw[16000];
    int gtid = blockIdx.x * 256 + threadIdx.x;     // [0, 262144)

    // ---- P1: occupancy bitmask (2 voxels/thread) + weight-frag packing ----
    #pragma unroll
    for (int it = 0; it < 2; it++) {
        int g = gtid + it * NTH;
        int b = g >> 16, n = g & 65535;
        if (n < nvv[b]) {
            const int* cp = xyz + (size_t)g * 3;
            int lin = cp[0] * (GG * GG) + cp[1] * GG + cp[2];
            atomicOr(&mask[(b << 13) + (lin >> 5)], 1u << (lin & 31));
        }
    }
    if (gtid < 2 * 14 * 512) {
        int bsel = gtid / (14 * 512);
        int idx  = gtid - bsel * (14 * 512);
        const float* w = bsel ? w1 : w0;
        int i = idx >> 9;
        int rem = idx & 511;
        int L = rem >> 3, j = rem & 7;
        int quad = L >> 4, nn = L & 15;
        int off = 2 * i + (quad >> 1);
        int c = ((quad & 1) << 3) + j;
        float vw = (off < 27) ? w[(off * 16 + c) * 16 + nn] : 0.f;
        wfr[gtid] = f2bf(vw);
    }
    gbar(bar);

    // ---- P2: scan (blocks 0..7, one batch each) ----
    if (blockIdx.x < 8) {
        int b = blockIdx.x;
        const uint32_t* mb = mask + (size_t)b * NW;
        int2* wb = mwb + (size_t)b * NW;
        int t = threadIdx.x;
        int* sc = (int*)smraw;

        uint32_t wvv[32];
        int cnts[32];
        int local = 0;
        #pragma unroll
        for (int i = 0; i < 32; i++) {
            wvv[i] = mb[t * 32 + i];
            cnts[i] = __popc(wvv[i]);
            local += cnts[i];
        }
        sc[t] = local;
        __syncthreads();
        for (int off = 1; off < 256; off <<= 1) {
            int v = (t >= off) ? sc[t - off] : 0;
            __syncthreads();
            sc[t] += v;
            __syncthreads();
        }
        int base = sc[t] - local;   // exclusive
        #pragma unroll
        for (int i = 0; i < 32; i++) {
            wb[t * 32 + i] = make_int2((int)wvv[i], base);
            base += cnts[i];
        }
    }
    gbar(bar);

    // ---- P3: permutation + gather feats -> rank-sorted bf16 + rinv ----
    #pragma unroll
    for (int it = 0; it < 2; it++) {
        int g = gtid + it * NTH;
        int b = g >> 16, n = g & 65535;
        int cnt = nvv[b];
        unsigned short* sfb = sfA + (size_t)b * NS * 16;
        if (n < cnt) {
            const int* cp = xyz + (size_t)g * 3;
            int lin = cp[0] * (GG * GG) + cp[1] * GG + cp[2];
            int r = site_rank2(mwb + (size_t)b * NW, lin);
            srow[(size_t)b * NN + r] = make_int2(lin, n);
            rinv[g] = r;
            const float4* fp = (const float4*)(feats + (size_t)g * 16);
            float4 f0 = fp[0], f1 = fp[1], f2 = fp[2], f3 = fp[3];
            uint4 lo = make_uint4(pk2(f0.x, f0.y), pk2(f0.z, f0.w),
                                  pk2(f1.x, f1.y), pk2(f1.z, f1.w));
            uint4 hi = make_uint4(pk2(f2.x, f2.y), pk2(f2.z, f2.w),
                                  pk2(f3.x, f3.y), pk2(f3.z, f3.w));
            *(uint4*)(sfb + (size_t)r * 16)     = lo;
            *(uint4*)(sfb + (size_t)r * 16 + 8) = hi;
        } else {
            uint4 z = make_uint4(0, 0, 0, 0);
            *(uint4*)(sfb + (size_t)n * 16)     = z;
            *(uint4*)(sfb + (size_t)n * 16 + 8) = z;
        }
    }
    // zero sentinel rows (row NN) of both sorted buffers
    if (gtid < 128)
        sfA[(size_t)(gtid >> 4) * NS * 16 + (size_t)NN * 16 + (gtid & 15)] = 0;
    else if (gtid < 256) {
        int q = gtid - 128;
        sfB[(size_t)(q >> 4) * NS * 16 + (size_t)NN * 16 + (q & 15)] = 0;
    }
    gbar(bar);

    // ---- P4: conv layer 1 ----
    conv_phase(sfA, srow, nvv, mwb, wfr, nw0, bufPre, stats1, smraw);
    gbar(bar);

    // ---- P5: BN1 + ReLU -> sorted bf16 (sfB) ----
    {
        float* sbs  = (float*)smraw;
        float* sums = (float*)(smraw + 128);
        compute_sb(stats1, nvv, gamma0, beta0, sbs, sums);
        #pragma unroll
        for (int it = 0; it < 2; it++) {
            int g = gtid + it * NTH;
            int b = g >> 16, r = g & 65535;
            int cnt = nvv[b];
            uint4 lo = make_uint4(0, 0, 0, 0), hi = lo;
            if (r < cnt) {
                const uint4* ip = (const uint4*)(bufPre + (size_t)g * 16);
                uint4 xl = ip[0], xh = ip[1];
                float y[16];
                #pragma unroll
                for (int c = 0; c < 16; c++) {
                    unsigned u = (c < 8) ? ((const unsigned*)&xl)[c >> 1]
                                         : ((const unsigned*)&xh)[(c - 8) >> 1];
                    unsigned short sv = (c & 1) ? (unsigned short)(u >> 16)
                                                : (unsigned short)(u & 0xffff);
                    y[c] = fmaxf(fmaf(bf2f(sv), sbs[c], sbs[16 + c]), 0.f);
                }
                lo = make_uint4(pk2(y[0], y[1]), pk2(y[2], y[3]),
                                pk2(y[4], y[5]), pk2(y[6], y[7]));
                hi = make_uint4(pk2(y[8], y[9]), pk2(y[10], y[11]),
                                pk2(y[12], y[13]), pk2(y[14], y[15]));
            }
            unsigned short* op = sfB + ((size_t)b * NS + r) * 16;
            *(uint4*)op       = lo;
            *(uint4*)(op + 8) = hi;
        }
    }
    gbar(bar);

    // ---- P6: conv layer 2 ----
    conv_phase(sfB, srow, nvv, mwb, wfr + 14 * 512, nw1, bufPre, stats2, smraw);
    gbar(bar);

    // ---- P7: BN2 + ReLU, n-indexed coalesced output ----
    {
        float* sbs  = (float*)smraw;
        float* sums = (float*)(smraw + 128);
        compute_sb(stats2, nvv, gamma1, beta1, sbs, sums);
        #pragma unroll
        for (int it = 0; it < 2; it++) {
            int g = gtid + it * NTH;
            int b = g >> 16, n = g & 65535;
            int cnt = nvv[b];
            float4* op = (float4*)(out + (size_t)g * 16);
            if (n < cnt) {
                int r = rinv[g];
                const uint4* ip = (const uint4*)(bufPre + ((size_t)b * NN + r) * 16);
                uint4 xl = ip[0], xh = ip[1];
                float y[16];
                #pragma unroll
                for (int c = 0; c < 16; c++) {
                    unsigned u = (c < 8) ? ((const unsigned*)&xl)[c >> 1]
                                         : ((const unsigned*)&xh)[(c - 8) >> 1];
                    unsigned short sv = (c & 1) ? (unsigned short)(u >> 16)
                                                : (unsigned short)(u & 0xffff);
                    y[c] = fmaxf(fmaf(bf2f(sv), sbs[c], sbs[16 + c]), 0.f);
                }
                op[0] = make_float4(y[0],  y[1],  y[2],  y[3]);
                op[1] = make_float4(y[4],  y[5],  y[6],  y[7]);
                op[2] = make_float4(y[8],  y[9],  y[10], y[11]);
                op[3] = make_float4(y[12], y[13], y[14], y[15]);
            } else {
                float4 z = make_float4(0.f, 0.f, 0.f, 0.f);
                op[0] = z; op[1] = z; op[2] = z; op[3] = z;
            }
        }
    }
}

// ---------------------------------------------------------------------------
extern "C" void kernel_launch(void* const* d_in, const int* in_sizes, int n_in,
                              void* d_out, int out_size, void* d_ws, size_t ws_size,
                              hipStream_t stream)
{
    const float* feats  = (const float*)d_in[0];
    const int*   xyz    = (const int*)d_in[1];
    const int*   nvv    = (const int*)d_in[2];
    const float* w0     = (const float*)d_in[3];
    const float* w1     = (const float*)d_in[4];
    const float* nw0    = (const float*)d_in[5];
    const float* nw1    = (const float*)d_in[6];
    const float* gamma0 = (const float*)d_in[7];
    const float* beta0  = (const float*)d_in[8];
    const float* gamma1 = (const float*)d_in[9];
    const float* beta1  = (const float*)d_in[10];
    float* out = (float*)d_out;

    char* ws = (char*)d_ws;
    uint32_t* mask    = (uint32_t*)ws;       ws += (size_t)NB * NW * 4;        // 256 KB (memset 0)
    float*    stats1  = (float*)ws;          ws += 16 * 32 * 4;                // 2 KB  (memset 0)
    float*    stats2  = (float*)ws;          ws += 16 * 32 * 4;                // 2 KB  (memset 0)
    unsigned* bar     = (unsigned*)ws;       ws += 256;                        // 256 B (memset 0)
    int2*     mwb     = (int2*)ws;           ws += (size_t)NB * NW * 8;        // 512 KB
    int2*     srow    = (int2*)ws;           ws += (size_t)NB * NN * 8;        // 4 MB
    unsigned short* sfA = (unsigned short*)ws; ws += (size_t)NB * NS * 16 * 2; // 16.8 MB
    unsigned short* sfB = (unsigned short*)ws; ws += (size_t)NB * NS * 16 * 2; // 16.8 MB
    unsigned short* bufPre = (unsigned short*)ws; ws += (size_t)NB * NN * 16 * 2; // 16 MB
    unsigned short* wfr = (unsigned short*)ws; ws += (size_t)2 * 14 * 512 * 2; // 28 KB
    int*      rinv    = (int*)ws;            ws += (size_t)NB * NN * 4;        // 2 MB

    // zero mask + stats + barrier state in one memset
    hipMemsetAsync(mask, 0, (size_t)NB * NW * 4 + 16 * 32 * 4 * 2 + 256, stream);

    mega_kernel<<<NBLKC, 256, 0, stream>>>(
        feats, xyz, nvv, w0, w1, nw0, nw1,
        gamma0, beta0, gamma1, beta1, out,
        mask, stats1, stats2, bar, mwb, srow, sfA, sfB, bufPre, wfr, rinv);
}

// Round 8
// 257.409 us; speedup vs baseline: 8.2288x; 8.2288x over previous
//
#include <hip/hip_runtime.h>
#include <cstdint>
#include <cstddef>

#define NB 8
#define NN 65536
#define NS (NN + 16)         // sorted-buffer row stride (row NN = zero sentinel)
#define GG 64
#define GG3 (GG*GG*GG)
#define NW (GG3/32)          // 8192 mask words per batch
#define NBLKC 2048           // conv blocks (8/CU resident at 64 VGPR + 16KB LDS)
#define EPSC 1e-3f

typedef __bf16 bf16x8 __attribute__((ext_vector_type(8)));
typedef float  f32x4  __attribute__((ext_vector_type(4)));
typedef unsigned uint32x4 __attribute__((ext_vector_type(4)));

__device__ __forceinline__ unsigned short f2bf(float f) {
    unsigned u = __builtin_bit_cast(unsigned, f);
    unsigned r = (u + 0x7fffu + ((u >> 16) & 1u)) >> 16;
    return (unsigned short)r;
}
__device__ __forceinline__ unsigned pk2(float a, float b) {
    return (unsigned)f2bf(a) | ((unsigned)f2bf(b) << 16);
}
__device__ __forceinline__ float bf2f(unsigned short s) {
    return __builtin_bit_cast(float, (unsigned)s << 16);
}

__device__ __forceinline__ int site_rank2(const int2* __restrict__ mwb, int lin) {
    int2 mw = mwb[lin >> 5];
    uint32_t w = (uint32_t)mw.x;
    uint32_t bit = 1u << (lin & 31);
    if (!(w & bit)) return -1;
    return mw.y + __popc(w & (bit - 1u));
}

// ---------------------------------------------------------------------------
// K12: fused mask-build (LDS atomics) + scan -> mwb. One block per batch.
// Also: weight-fragment packing (blocks 0,1) and stats zeroing (block 0).
// Replaces K1 + K2 + the workspace memset (3 dispatches -> 1).
// ---------------------------------------------------------------------------
__global__ __launch_bounds__(1024) void mask_scan_kernel(
    const int* __restrict__ xyz, const int* __restrict__ nvv,
    int2* __restrict__ mwb,
    const float* __restrict__ w0, const float* __restrict__ w1,
    unsigned short* __restrict__ wf,
    float* __restrict__ stats1, float* __restrict__ stats2)
{
    __shared__ uint32_t lmask[NW];     // 32 KB occupancy bitmap for this batch
    __shared__ int sc[1024];
    int b = blockIdx.x;
    int t = threadIdx.x;

    #pragma unroll
    for (int i = 0; i < NW / 1024; i++) lmask[t + i * 1024] = 0u;
    if (b == 0 && t < 512) { stats1[t] = 0.f; stats2[t] = 0.f; }
    __syncthreads();

    int cnt = nvv[b];
    #pragma unroll 4
    for (int n = t; n < NN; n += 1024) {
        if (n < cnt) {
            const int* cp = xyz + ((size_t)b * NN + n) * 3;
            int lin = cp[0] * (GG * GG) + cp[1] * GG + cp[2];
            atomicOr(&lmask[lin >> 5], 1u << (lin & 31));
        }
    }
    __syncthreads();

    // per-thread popcount over 8 words + block scan
    uint32_t wv[8];
    int cnts[8];
    int local = 0;
    #pragma unroll
    for (int i = 0; i < 8; i++) {
        wv[i] = lmask[t * 8 + i];
        cnts[i] = __popc(wv[i]);
        local += cnts[i];
    }
    sc[t] = local;
    __syncthreads();
    for (int off = 1; off < 1024; off <<= 1) {
        int v = (t >= off) ? sc[t - off] : 0;
        __syncthreads();
        sc[t] += v;
        __syncthreads();
    }
    int base = sc[t] - local;   // exclusive
    int2* wb = mwb + (size_t)b * NW;
    #pragma unroll
    for (int i = 0; i < 8; i++) {
        wb[t * 8 + i] = make_int2((int)wv[i], base);
        base += cnts[i];
    }

    // weight packing (blocks 0,1)
    if (b < 2) {
        const float* w = b ? w1 : w0;
        unsigned short* o = wf + b * 14 * 512;
        for (int idx = t; idx < 14 * 512; idx += 1024) {
            int i = idx >> 9;
            int rem = idx & 511;
            int L = rem >> 3, j = rem & 7;
            int quad = L >> 4, nn = L & 15;
            int off = 2 * i + (quad >> 1);
            int c = ((quad & 1) << 3) + j;
            float v = (off < 27) ? w[(off * 16 + c) * 16 + nn] : 0.f;
            o[idx] = f2bf(v);
        }
    }
}

// ---------------------------------------------------------------------------
// K3: permutation + gather feats (fp32) into rank-sorted bf16 rows.
// Also writes rinv[n] = rank. Big writes are nontemporal (write-once;
// cross-kernel L2 reuse impossible on per-XCD L2s).
// ---------------------------------------------------------------------------
__global__ __launch_bounds__(256) void perm_gather_kernel(
    const int* __restrict__ xyz, const int* __restrict__ nvv,
    const int2* __restrict__ mwb,
    const float* __restrict__ feats,
    int2* __restrict__ srow,
    unsigned short* __restrict__ sfeats,
    int* __restrict__ rinv)
{
    int b = blockIdx.y;
    int n = blockIdx.x * 256 + threadIdx.x;
    int cnt = nvv[b];
    unsigned short* sfb = sfeats + (size_t)b * NS * 16;
    if (blockIdx.x == 0 && threadIdx.x < 16)
        sfb[(size_t)NN * 16 + threadIdx.x] = 0;     // sentinel row
    if (n < cnt) {
        const int* cp = xyz + ((size_t)b * NN + n) * 3;
        int lin = cp[0] * (GG * GG) + cp[1] * GG + cp[2];
        int r = site_rank2(mwb + (size_t)b * NW, lin);
        srow[(size_t)b * NN + r] = make_int2(lin, n);
        rinv[(size_t)b * NN + n] = r;
        const float4* fp = (const float4*)(feats + ((size_t)b * NN + n) * 16);
        float4 f0 = fp[0], f1 = fp[1], f2 = fp[2], f3 = fp[3];
        uint32x4 lo = { pk2(f0.x, f0.y), pk2(f0.z, f0.w),
                        pk2(f1.x, f1.y), pk2(f1.z, f1.w) };
        uint32x4 hi = { pk2(f2.x, f2.y), pk2(f2.z, f2.w),
                        pk2(f3.x, f3.y), pk2(f3.z, f3.w) };
        __builtin_nontemporal_store(lo, (uint32x4*)(sfb + (size_t)r * 16));
        __builtin_nontemporal_store(hi, (uint32x4*)(sfb + (size_t)r * 16 + 8));
    } else {
        uint32x4 z = { 0u, 0u, 0u, 0u };
        __builtin_nontemporal_store(z, (uint32x4*)(sfb + (size_t)n * 16));
        __builtin_nontemporal_store(z, (uint32x4*)(sfb + (size_t)n * 16 + 8));
    }
}

// ---------------------------------------------------------------------------
// K4/K6: MFMA sparse conv, round-6 body (64 VGPR, spill-free), XCD-locality
// tile mapping (batch = blockIdx&7). New: nontemporal outbuf stores so the
// 16MB write-once pre-BN stream doesn't evict the L2-resident gather set.
// ---------------------------------------------------------------------------
__global__ __launch_bounds__(256, 4) void conv_mfma_kernel(
    const unsigned short* __restrict__ sfeats,  // (B,NS,16) bf16 rank-sorted
    const int2*     __restrict__ srow,          // (B,NN) rank -> {lin, n}
    const int*      __restrict__ nvv,
    const int2*     __restrict__ mwb,           // (B,NW) {mask word, base}
    const unsigned short* __restrict__ wfrag,   // 14*512 bf16 B-frags
    const float*    __restrict__ nw,            // (27,)
    unsigned short* __restrict__ outbuf,        // (B,NN,16) bf16 pre-BN sorted
    float*          __restrict__ stats)         // [16][32] striped accumulators
{
    int lane = threadIdx.x & 63;
    int wv = threadIdx.x >> 6;
    int m = lane & 15, quad = lane >> 4;       // compute-phase layout
    int v = lane & 31, h = lane >> 5;          // rank-phase layout

    // XCD-aware mapping: batch = XCD slot; 256 blocks x 4 waves per batch
    int b    = blockIdx.x & 7;                 // batch == XCD (heuristic)
    int widb = (blockIdx.x >> 3) * 4 + wv;     // wave-in-batch [0, 1024)

    __shared__ int   jj[4][32][29];            // stride 29: conflict-free-ish
    __shared__ float rrl[4][32];
    __shared__ float red[4][32];
    __shared__ float lnw[27];

    if (threadIdx.x < 27) lnw[threadIdx.x] = nw[threadIdx.x];

    // B-fragments: loaded once per wave, held in registers
    bf16x8 bfr[14];
    #pragma unroll
    for (int i = 0; i < 14; i++)
        bfr[i] = *(const bf16x8*)(wfrag + i * 512 + lane * 8);
    __syncthreads();

    float psum = 0.f, psq = 0.f;
    int coff = (quad & 1) << 3;

    // wave-uniform per-batch bases (SGPR-resident)
    int cnt = nvv[b];
    const int2* mb = mwb + (size_t)b * NW;
    const unsigned short* fb = sfeats + (size_t)b * NS * 16;
    const int2* sr = srow + (size_t)b * NN;

    #pragma unroll 1
    for (int k = 0; k < 2; k++) {
        int r0 = (widb + k * 1024) << 5;       // 32 ranks per pair-tile
        if (r0 >= cnt) continue;

        // ---- rank phase: slot = (voxel v, column c = 2t + h), c in [0,9) ----
        int Rv = r0 + v;
        bool vld = Rv < cnt;
        int lin = vld ? sr[Rv].x : 0;
        int x = lin >> 12, y = (lin >> 6) & 63, z = lin & 63;
        int zb = z & 31;
        float nc = 0.f;
        #pragma unroll
        for (int t = 0; t < 5; t++) {
            int c = 2 * t + h;
            bool cok = c < 9;
            int cc = cok ? c : 0;
            int dx = cc / 3 - 1, dy = cc % 3 - 1;
            int nx = x + dx, ny = y + dy;
            bool colok = cok & ((unsigned)nx < 64u) & ((unsigned)ny < 64u);
            int wdi = colok ? (((nx << 12) + (ny << 6) + z) >> 5) : 0;

            int2 mw = make_int2(0, 0);
            if (vld & colok) mw = mb[wdi];
            // rare 2nd word when z-1/z+1 crosses the 32-bit boundary
            bool need2 = vld & colok & (((zb == 0) & (z > 0)) | ((zb == 31) & (z < 63)));
            int w2 = wdi + ((zb == 0) ? -1 : 1);
            int2 mw2 = make_int2(0, 0);
            if (need2) mw2 = mb[w2];

            #pragma unroll
            for (int dz = -1; dz <= 1; dz++) {
                int zz = z + dz;
                bool zok = (unsigned)zz < 64u;
                bool same = (dz == 0) | ((dz < 0) ? (zb != 0) : (zb != 31));
                int2 word = same ? mw : mw2;
                int bb = zz & 31;
                uint32_t wm = (uint32_t)word.x;
                bool hit = vld & colok & zok & ((wm >> bb) & 1u);
                int rnk = word.y + __popc(wm & ((1u << bb) - 1u));
                int off = cc * 3 + dz + 1;
                int jv = hit ? rnk : NN;
                if (cok) {
                    jj[wv][v][off] = jv;
                    nc += hit ? lnw[off] : 0.f;
                }
            }
        }
        nc += __shfl_xor(nc, 32, 64);
        if (lane < 32) rrl[wv][v] = 1.f / (1.f + fabsf(nc));

        // ---- compute phase: 28 gathers + 28 MFMAs (two independent chains) ----
        f32x4 acc0 = {0.f, 0.f, 0.f, 0.f};
        f32x4 acc1 = {0.f, 0.f, 0.f, 0.f};
        #pragma unroll
        for (int i = 0; i < 14; i++) {
            int off = 2 * i + (quad >> 1);
            int idx = off < 27 ? off : 28;
            int j0 = jj[wv][m][idx];      j0 = (off < 27) ? j0 : NN;
            int j1 = jj[wv][m + 16][idx]; j1 = (off < 27) ? j1 : NN;
            bf16x8 a0 = *(const bf16x8*)(fb + (size_t)j0 * 16 + coff);
            bf16x8 a1 = *(const bf16x8*)(fb + (size_t)j1 * 16 + coff);
            acc0 = __builtin_amdgcn_mfma_f32_16x16x32_bf16(a0, bfr[i], acc0, 0, 0, 0);
            acc1 = __builtin_amdgcn_mfma_f32_16x16x32_bf16(a1, bfr[i], acc1, 0, 0, 0);
        }

        // ---- epilogue: D[row=quad*4+r][ch=m], both halves; NT stores ----
        #pragma unroll
        for (int hh = 0; hh < 2; hh++) {
            int rbase = r0 + (hh << 4);
            #pragma unroll
            for (int r4 = 0; r4 < 4; r4++) {
                int row = (quad << 2) + r4;
                float tval = (hh ? acc1[r4] : acc0[r4]) * rrl[wv][(hh << 4) + row];
                psum += tval; psq += tval * tval;
                int Rr = rbase + row;
                if (Rr < cnt)
                    __builtin_nontemporal_store(
                        f2bf(tval), &outbuf[((size_t)b * NN + Rr) * 16 + m]);
            }
        }
    }

    // ---- BN partial stats: block reduce, striped atomics ----
    psum += __shfl_xor(psum, 16, 64); psum += __shfl_xor(psum, 32, 64);
    psq  += __shfl_xor(psq, 16, 64);  psq  += __shfl_xor(psq, 32, 64);
    if (lane < 16) { red[wv][lane] = psum; red[wv][16 + lane] = psq; }
    __syncthreads();
    if (threadIdx.x < 32) {
        float vv = red[0][threadIdx.x] + red[1][threadIdx.x] +
                   red[2][threadIdx.x] + red[3][threadIdx.x];
        atomicAdd(&stats[(blockIdx.x & 15) * 32 + threadIdx.x], vv);
    }
}

// ---------------------------------------------------------------------------
// shared helper: derive per-channel scale/bias from striped stats into LDS
// ---------------------------------------------------------------------------
__device__ __forceinline__ void compute_sb(
    const float* __restrict__ stats, const int* __restrict__ nvv,
    const float* __restrict__ gamma, const float* __restrict__ beta,
    float* sbs /*LDS[32]*/, float* sums /*LDS[32]*/)
{
    int tid = threadIdx.x;
    if (tid < 32) {
        float v = 0.f;
        #pragma unroll
        for (int s = 0; s < 16; s++) v += stats[s * 32 + tid];
        sums[tid] = v;
    }
    __syncthreads();
    if (tid < 16) {
        float cnt = 0.f;
        #pragma unroll
        for (int b = 0; b < NB; b++) cnt += (float)nvv[b];
        float mean = sums[tid] / cnt;
        float var  = fmaxf(sums[16 + tid] / cnt - mean * mean, 0.f);
        float scv = gamma[tid] * rsqrtf(var + EPSC);
        sbs[tid]      = scv;
        sbs[16 + tid] = beta[tid] - mean * scv;
    }
    __syncthreads();
}

// ---------------------------------------------------------------------------
// K5: BN1+ReLU on sorted bf16 -> sorted bf16 (rows [cnt,NN] zeroed); sb fused
// ---------------------------------------------------------------------------
__global__ __launch_bounds__(256) void bnrelu_sorted_kernel(
    const unsigned short* __restrict__ in, const float* __restrict__ stats,
    const int* __restrict__ nvv,
    const float* __restrict__ gamma, const float* __restrict__ beta,
    unsigned short* __restrict__ outb)
{
    __shared__ float sbs[32];
    __shared__ float sums[32];
    compute_sb(stats, nvv, gamma, beta, sbs, sums);

    int b = blockIdx.y;
    int r = blockIdx.x * 256 + threadIdx.x;
    if (r > NN) return;
    int cnt = nvv[b];
    uint32x4 lo = { 0u, 0u, 0u, 0u }, hi = lo;
    if (r < cnt) {
        const uint4* ip = (const uint4*)(in + ((size_t)b * NN + r) * 16);
        uint4 xl = ip[0], xh = ip[1];
        float y[16];
        #pragma unroll
        for (int c = 0; c < 16; c++) {
            unsigned u = (c < 8) ? ((const unsigned*)&xl)[c >> 1]
                                 : ((const unsigned*)&xh)[(c - 8) >> 1];
            unsigned short sv = (c & 1) ? (unsigned short)(u >> 16)
                                        : (unsigned short)(u & 0xffff);
            y[c] = fmaxf(fmaf(bf2f(sv), sbs[c], sbs[16 + c]), 0.f);
        }
        lo = (uint32x4){ pk2(y[0], y[1]), pk2(y[2], y[3]),
                         pk2(y[4], y[5]), pk2(y[6], y[7]) };
        hi = (uint32x4){ pk2(y[8], y[9]), pk2(y[10], y[11]),
                         pk2(y[12], y[13]), pk2(y[14], y[15]) };
    }
    unsigned short* op = outb + ((size_t)b * NS + r) * 16;
    __builtin_nontemporal_store(lo, (uint32x4*)op);
    __builtin_nontemporal_store(hi, (uint32x4*)(op + 8));
}

// ---------------------------------------------------------------------------
// K7: final BN2+ReLU, n-indexed: coalesced NT HBM writes, scattered L3 reads.
// ---------------------------------------------------------------------------
__global__ __launch_bounds__(256) void final_out_kernel(
    const unsigned short* __restrict__ in,     // (B,NN,16) bf16 pre-BN sorted
    const int* __restrict__ rinv,              // (B,NN) n -> rank
    const float* __restrict__ stats, const int* __restrict__ nvv,
    const float* __restrict__ gamma, const float* __restrict__ beta,
    float* __restrict__ out)
{
    __shared__ float sbs[32];
    __shared__ float sums[32];
    compute_sb(stats, nvv, gamma, beta, sbs, sums);

    int b = blockIdx.y;
    int n = blockIdx.x * 256 + threadIdx.x;
    int cnt = nvv[b];
    f32x4* op = (f32x4*)(out + ((size_t)b * NN + n) * 16);
    if (n < cnt) {
        int r = rinv[(size_t)b * NN + n];
        const uint4* ip = (const uint4*)(in + ((size_t)b * NN + r) * 16);
        uint4 xl = ip[0], xh = ip[1];
        float y[16];
        #pragma unroll
        for (int c = 0; c < 16; c++) {
            unsigned u = (c < 8) ? ((const unsigned*)&xl)[c >> 1]
                                 : ((const unsigned*)&xh)[(c - 8) >> 1];
            unsigned short sv = (c & 1) ? (unsigned short)(u >> 16)
                                        : (unsigned short)(u & 0xffff);
            y[c] = fmaxf(fmaf(bf2f(sv), sbs[c], sbs[16 + c]), 0.f);
        }
        __builtin_nontemporal_store((f32x4){y[0],  y[1],  y[2],  y[3]},  op);
        __builtin_nontemporal_store((f32x4){y[4],  y[5],  y[6],  y[7]},  op + 1);
        __builtin_nontemporal_store((f32x4){y[8],  y[9],  y[10], y[11]}, op + 2);
        __builtin_nontemporal_store((f32x4){y[12], y[13], y[14], y[15]}, op + 3);
    } else {
        f32x4 z = { 0.f, 0.f, 0.f, 0.f };
        __builtin_nontemporal_store(z, op);
        __builtin_nontemporal_store(z, op + 1);
        __builtin_nontemporal_store(z, op + 2);
        __builtin_nontemporal_store(z, op + 3);
    }
}

// ---------------------------------------------------------------------------
extern "C" void kernel_launch(void* const* d_in, const int* in_sizes, int n_in,
                              void* d_out, int out_size, void* d_ws, size_t ws_size,
                              hipStream_t stream)
{
    const float* feats  = (const float*)d_in[0];
    const int*   xyz    = (const int*)d_in[1];
    const int*   nvv    = (const int*)d_in[2];
    const float* w0     = (const float*)d_in[3];
    const float* w1     = (const float*)d_in[4];
    const float* nw0    = (const float*)d_in[5];
    const float* nw1    = (const float*)d_in[6];
    const float* gamma0 = (const float*)d_in[7];
    const float* beta0  = (const float*)d_in[8];
    const float* gamma1 = (const float*)d_in[9];
    const float* beta1  = (const float*)d_in[10];
    float* out = (float*)d_out;

    char* ws = (char*)d_ws;
    float*    stats1  = (float*)ws;          ws += 16 * 32 * 4;                // 2 KB (zeroed by K12)
    float*    stats2  = (float*)ws;          ws += 16 * 32 * 4;                // 2 KB (zeroed by K12)
    int2*     mwb     = (int2*)ws;           ws += (size_t)NB * NW * 8;        // 512 KB
    int2*     srow    = (int2*)ws;           ws += (size_t)NB * NN * 8;        // 4 MB
    unsigned short* sfA = (unsigned short*)ws; ws += (size_t)NB * NS * 16 * 2; // 16.8 MB
    unsigned short* sfB = (unsigned short*)ws; ws += (size_t)NB * NS * 16 * 2; // 16.8 MB
    unsigned short* bufPre = (unsigned short*)ws; ws += (size_t)NB * NN * 16 * 2; // 16 MB
    unsigned short* wfr = (unsigned short*)ws; ws += (size_t)2 * 14 * 512 * 2; // 28 KB
    int*      rinv    = (int*)ws;            ws += (size_t)NB * NN * 4;        // 2 MB

    // K12: mask(LDS)+scan+weight-pack+stats-zero (replaces memset+K1+K2)
    mask_scan_kernel<<<NB, 1024, 0, stream>>>(
        xyz, nvv, mwb, w0, w1, wfr, stats1, stats2);

    dim3 gridBN(NN / 256, NB);
    perm_gather_kernel<<<gridBN, 256, 0, stream>>>(xyz, nvv, mwb, feats, srow, sfA, rinv);

    // Layer 1: sorted bf16 in -> sorted bf16 (pre-BN) out + stats1
    conv_mfma_kernel<<<NBLKC, 256, 0, stream>>>(
        sfA, srow, nvv, mwb, wfr, nw0, bufPre, stats1);
    bnrelu_sorted_kernel<<<dim3(NN / 256 + 1, NB), 256, 0, stream>>>(
        bufPre, stats1, nvv, gamma0, beta0, sfB);

    // Layer 2: sorted bf16 in -> sorted bf16 (pre-BN) out + stats2
    conv_mfma_kernel<<<NBLKC, 256, 0, stream>>>(
        sfB, srow, nvv, mwb, wfr + 14 * 512, nw1, bufPre, stats2);

    // Final: BN2+ReLU, coalesced n-order NT writes, zero invalid rows
    final_out_kernel<<<dim3(NN / 256, NB), 256, 0, stream>>>(
        bufPre, rinv, stats2, nvv, gamma1, beta1, out);
}

// Round 9
// 234.711 us; speedup vs baseline: 9.0246x; 1.0967x over previous
//
#include <hip/hip_runtime.h>
#include <cstdint>
#include <cstddef>

#define NB 8
#define NN 65536
#define NS (NN + 16)         // sorted-buffer row stride (row NN = zero sentinel)
#define GG 64
#define GG3 (GG*GG*GG)
#define NW (GG3/32)          // 8192 mask words per batch
#define NBLKC 2048           // conv blocks (8/CU resident at 64 VGPR + 16KB LDS)
#define EPSC 1e-3f

typedef __bf16 bf16x8 __attribute__((ext_vector_type(8)));
typedef float  f32x4  __attribute__((ext_vector_type(4)));

__device__ __forceinline__ unsigned short f2bf(float f) {
    unsigned u = __builtin_bit_cast(unsigned, f);
    unsigned r = (u + 0x7fffu + ((u >> 16) & 1u)) >> 16;
    return (unsigned short)r;
}
__device__ __forceinline__ unsigned pk2(float a, float b) {
    return (unsigned)f2bf(a) | ((unsigned)f2bf(b) << 16);
}
__device__ __forceinline__ float bf2f(unsigned short s) {
    return __builtin_bit_cast(float, (unsigned)s << 16);
}

__device__ __forceinline__ int site_rank2(const int2* __restrict__ mwb, int lin) {
    int2 mw = mwb[lin >> 5];
    uint32_t w = (uint32_t)mw.x;
    uint32_t bit = 1u << (lin & 31);
    if (!(w & bit)) return -1;
    return mw.y + __popc(w & (bit - 1u));
}

// ---------------------------------------------------------------------------
// K12: fused mask-build (LDS atomics) + scan -> mwb. One block per batch.
// Also: weight-fragment packing (blocks 0,1) and stats zeroing (block 0).
// Replaces memset + K1 + K2 (3 dispatches -> 1). Verified in round 8.
// ---------------------------------------------------------------------------
__global__ __launch_bounds__(1024) void mask_scan_kernel(
    const int* __restrict__ xyz, const int* __restrict__ nvv,
    int2* __restrict__ mwb,
    const float* __restrict__ w0, const float* __restrict__ w1,
    unsigned short* __restrict__ wf,
    float* __restrict__ stats1, float* __restrict__ stats2)
{
    __shared__ uint32_t lmask[NW];     // 32 KB occupancy bitmap for this batch
    __shared__ int sc[1024];
    int b = blockIdx.x;
    int t = threadIdx.x;

    #pragma unroll
    for (int i = 0; i < NW / 1024; i++) lmask[t + i * 1024] = 0u;
    if (b == 0 && t < 512) { stats1[t] = 0.f; stats2[t] = 0.f; }
    __syncthreads();

    int cnt = nvv[b];
    #pragma unroll 4
    for (int n = t; n < NN; n += 1024) {
        if (n < cnt) {
            const int* cp = xyz + ((size_t)b * NN + n) * 3;
            int lin = cp[0] * (GG * GG) + cp[1] * GG + cp[2];
            atomicOr(&lmask[lin >> 5], 1u << (lin & 31));
        }
    }
    __syncthreads();

    // per-thread popcount over 8 words + block scan
    uint32_t wv[8];
    int cnts[8];
    int local = 0;
    #pragma unroll
    for (int i = 0; i < 8; i++) {
        wv[i] = lmask[t * 8 + i];
        cnts[i] = __popc(wv[i]);
        local += cnts[i];
    }
    sc[t] = local;
    __syncthreads();
    for (int off = 1; off < 1024; off <<= 1) {
        int v = (t >= off) ? sc[t - off] : 0;
        __syncthreads();
        sc[t] += v;
        __syncthreads();
    }
    int base = sc[t] - local;   // exclusive
    int2* wb = mwb + (size_t)b * NW;
    #pragma unroll
    for (int i = 0; i < 8; i++) {
        wb[t * 8 + i] = make_int2((int)wv[i], base);
        base += cnts[i];
    }

    // weight packing (blocks 0,1)
    if (b < 2) {
        const float* w = b ? w1 : w0;
        unsigned short* o = wf + b * 14 * 512;
        for (int idx = t; idx < 14 * 512; idx += 1024) {
            int i = idx >> 9;
            int rem = idx & 511;
            int L = rem >> 3, j = rem & 7;
            int quad = L >> 4, nn = L & 15;
            int off = 2 * i + (quad >> 1);
            int c = ((quad & 1) << 3) + j;
            float v = (off < 27) ? w[(off * 16 + c) * 16 + nn] : 0.f;
            o[idx] = f2bf(v);
        }
    }
}

// ---------------------------------------------------------------------------
// K3: permutation + gather feats (fp32) into rank-sorted bf16 rows.
// Also writes rinv[n] = rank (for coalesced final output pass).
// ---------------------------------------------------------------------------
__global__ __launch_bounds__(256) void perm_gather_kernel(
    const int* __restrict__ xyz, const int* __restrict__ nvv,
    const int2* __restrict__ mwb,
    const float* __restrict__ feats,
    int2* __restrict__ srow,
    unsigned short* __restrict__ sfeats,
    int* __restrict__ rinv)
{
    int b = blockIdx.y;
    int n = blockIdx.x * 256 + threadIdx.x;
    int cnt = nvv[b];
    unsigned short* sfb = sfeats + (size_t)b * NS * 16;
    if (blockIdx.x == 0 && threadIdx.x < 16)
        sfb[(size_t)NN * 16 + threadIdx.x] = 0;     // sentinel row
    if (n < cnt) {
        const int* cp = xyz + ((size_t)b * NN + n) * 3;
        int lin = cp[0] * (GG * GG) + cp[1] * GG + cp[2];
        int r = site_rank2(mwb + (size_t)b * NW, lin);
        srow[(size_t)b * NN + r] = make_int2(lin, n);
        rinv[(size_t)b * NN + n] = r;
        const float4* fp = (const float4*)(feats + ((size_t)b * NN + n) * 16);
        float4 f0 = fp[0], f1 = fp[1], f2 = fp[2], f3 = fp[3];
        uint4 lo = make_uint4(pk2(f0.x, f0.y), pk2(f0.z, f0.w),
                              pk2(f1.x, f1.y), pk2(f1.z, f1.w));
        uint4 hi = make_uint4(pk2(f2.x, f2.y), pk2(f2.z, f2.w),
                              pk2(f3.x, f3.y), pk2(f3.z, f3.w));
        *(uint4*)(sfb + (size_t)r * 16)     = lo;
        *(uint4*)(sfb + (size_t)r * 16 + 8) = hi;
    } else {
        uint4 z = make_uint4(0, 0, 0, 0);
        *(uint4*)(sfb + (size_t)n * 16)     = z;
        *(uint4*)(sfb + (size_t)n * 16 + 8) = z;
    }
}

// ---------------------------------------------------------------------------
// K4/K6: MFMA sparse conv, round-6 body verbatim (64 VGPR, spill-free),
// XCD-locality tile mapping (batch = blockIdx&7 -> per-XCD L2 residency;
// confirmed by FETCH_SIZE 8.9MB vs 23.9MB non-mapped).
// ---------------------------------------------------------------------------
__global__ __launch_bounds__(256, 4) void conv_mfma_kernel(
    const unsigned short* __restrict__ sfeats,  // (B,NS,16) bf16 rank-sorted
    const int2*     __restrict__ srow,          // (B,NN) rank -> {lin, n}
    const int*      __restrict__ nvv,
    const int2*     __restrict__ mwb,           // (B,NW) {mask word, base}
    const unsigned short* __restrict__ wfrag,   // 14*512 bf16 B-frags
    const float*    __restrict__ nw,            // (27,)
    unsigned short* __restrict__ outbuf,        // (B,NN,16) bf16 pre-BN sorted
    float*          __restrict__ stats)         // [16][32] striped accumulators
{
    int lane = threadIdx.x & 63;
    int wv = threadIdx.x >> 6;
    int m = lane & 15, quad = lane >> 4;       // compute-phase layout
    int v = lane & 31, h = lane >> 5;          // rank-phase layout

    // XCD-aware mapping: batch = XCD slot; 256 blocks x 4 waves per batch
    int b    = blockIdx.x & 7;                 // batch == XCD (heuristic)
    int widb = (blockIdx.x >> 3) * 4 + wv;     // wave-in-batch [0, 1024)

    __shared__ int   jj[4][32][29];            // stride 29: conflict-free-ish
    __shared__ float rrl[4][32];
    __shared__ float red[4][32];
    __shared__ float lnw[27];

    if (threadIdx.x < 27) lnw[threadIdx.x] = nw[threadIdx.x];

    // B-fragments: loaded once per wave, held in registers
    bf16x8 bfr[14];
    #pragma unroll
    for (int i = 0; i < 14; i++)
        bfr[i] = *(const bf16x8*)(wfrag + i * 512 + lane * 8);
    __syncthreads();

    float psum = 0.f, psq = 0.f;
    int coff = (quad & 1) << 3;

    // wave-uniform per-batch bases (SGPR-resident)
    int cnt = nvv[b];
    const int2* mb = mwb + (size_t)b * NW;
    const unsigned short* fb = sfeats + (size_t)b * NS * 16;
    const int2* sr = srow + (size_t)b * NN;

    #pragma unroll 1
    for (int k = 0; k < 2; k++) {
        int r0 = (widb + k * 1024) << 5;       // 32 ranks per pair-tile
        if (r0 >= cnt) continue;

        // ---- rank phase: slot = (voxel v, column c = 2t + h), c in [0,9) ----
        int Rv = r0 + v;
        bool vld = Rv < cnt;
        int lin = vld ? sr[Rv].x : 0;
        int x = lin >> 12, y = (lin >> 6) & 63, z = lin & 63;
        int zb = z & 31;
        float nc = 0.f;
        #pragma unroll
        for (int t = 0; t < 5; t++) {
            int c = 2 * t + h;
            bool cok = c < 9;
            int cc = cok ? c : 0;
            int dx = cc / 3 - 1, dy = cc % 3 - 1;
            int nx = x + dx, ny = y + dy;
            bool colok = cok & ((unsigned)nx < 64u) & ((unsigned)ny < 64u);
            int wdi = colok ? (((nx << 12) + (ny << 6) + z) >> 5) : 0;

            int2 mw = make_int2(0, 0);
            if (vld & colok) mw = mb[wdi];
            // rare 2nd word when z-1/z+1 crosses the 32-bit boundary
            bool need2 = vld & colok & (((zb == 0) & (z > 0)) | ((zb == 31) & (z < 63)));
            int w2 = wdi + ((zb == 0) ? -1 : 1);
            int2 mw2 = make_int2(0, 0);
            if (need2) mw2 = mb[w2];

            #pragma unroll
            for (int dz = -1; dz <= 1; dz++) {
                int zz = z + dz;
                bool zok = (unsigned)zz < 64u;
                bool same = (dz == 0) | ((dz < 0) ? (zb != 0) : (zb != 31));
                int2 word = same ? mw : mw2;
                int bb = zz & 31;
                uint32_t wm = (uint32_t)word.x;
                bool hit = vld & colok & zok & ((wm >> bb) & 1u);
                int rnk = word.y + __popc(wm & ((1u << bb) - 1u));
                int off = cc * 3 + dz + 1;
                int jv = hit ? rnk : NN;
                if (cok) {
                    jj[wv][v][off] = jv;
                    nc += hit ? lnw[off] : 0.f;
                }
            }
        }
        nc += __shfl_xor(nc, 32, 64);
        if (lane < 32) rrl[wv][v] = 1.f / (1.f + fabsf(nc));

        // ---- compute phase: 28 gathers + 28 MFMAs (two independent chains) ----
        f32x4 acc0 = {0.f, 0.f, 0.f, 0.f};
        f32x4 acc1 = {0.f, 0.f, 0.f, 0.f};
        #pragma unroll
        for (int i = 0; i < 14; i++) {
            int off = 2 * i + (quad >> 1);
            int idx = off < 27 ? off : 28;
            int j0 = jj[wv][m][idx];      j0 = (off < 27) ? j0 : NN;
            int j1 = jj[wv][m + 16][idx]; j1 = (off < 27) ? j1 : NN;
            bf16x8 a0 = *(const bf16x8*)(fb + (size_t)j0 * 16 + coff);
            bf16x8 a1 = *(const bf16x8*)(fb + (size_t)j1 * 16 + coff);
            acc0 = __builtin_amdgcn_mfma_f32_16x16x32_bf16(a0, bfr[i], acc0, 0, 0, 0);
            acc1 = __builtin_amdgcn_mfma_f32_16x16x32_bf16(a1, bfr[i], acc1, 0, 0, 0);
        }

        // ---- epilogue: D[row=quad*4+r][ch=m], both halves ----
        #pragma unroll
        for (int hh = 0; hh < 2; hh++) {
            int rbase = r0 + (hh << 4);
            #pragma unroll
            for (int r4 = 0; r4 < 4; r4++) {
                int row = (quad << 2) + r4;
                float tval = (hh ? acc1[r4] : acc0[r4]) * rrl[wv][(hh << 4) + row];
                psum += tval; psq += tval * tval;
                int Rr = rbase + row;
                if (Rr < cnt)
                    outbuf[((size_t)b * NN + Rr) * 16 + m] = f2bf(tval);
            }
        }
    }

    // ---- BN partial stats: block reduce, striped atomics ----
    psum += __shfl_xor(psum, 16, 64); psum += __shfl_xor(psum, 32, 64);
    psq  += __shfl_xor(psq, 16, 64);  psq  += __shfl_xor(psq, 32, 64);
    if (lane < 16) { red[wv][lane] = psum; red[wv][16 + lane] = psq; }
    __syncthreads();
    if (threadIdx.x < 32) {
        float vv = red[0][threadIdx.x] + red[1][threadIdx.x] +
                   red[2][threadIdx.x] + red[3][threadIdx.x];
        atomicAdd(&stats[(blockIdx.x & 15) * 32 + threadIdx.x], vv);
    }
}

// ---------------------------------------------------------------------------
// shared helper: derive per-channel scale/bias from striped stats into LDS
// ---------------------------------------------------------------------------
__device__ __forceinline__ void compute_sb(
    const float* __restrict__ stats, const int* __restrict__ nvv,
    const float* __restrict__ gamma, const float* __restrict__ beta,
    float* sbs /*LDS[32]*/, float* sums /*LDS[32]*/)
{
    int tid = threadIdx.x;
    if (tid < 32) {
        float v = 0.f;
        #pragma unroll
        for (int s = 0; s < 16; s++) v += stats[s * 32 + tid];
        sums[tid] = v;
    }
    __syncthreads();
    if (tid < 16) {
        float cnt = 0.f;
        #pragma unroll
        for (int b = 0; b < NB; b++) cnt += (float)nvv[b];
        float mean = sums[tid] / cnt;
        float var  = fmaxf(sums[16 + tid] / cnt - mean * mean, 0.f);
        float scv = gamma[tid] * rsqrtf(var + EPSC);
        sbs[tid]      = scv;
        sbs[16 + tid] = beta[tid] - mean * scv;
    }
    __syncthreads();
}

// ---------------------------------------------------------------------------
// K5: BN1+ReLU on sorted bf16 -> sorted bf16 (rows [cnt,NN] zeroed); sb fused
// ---------------------------------------------------------------------------
__global__ __launch_bounds__(256) void bnrelu_sorted_kernel(
    const unsigned short* __restrict__ in, const float* __restrict__ stats,
    const int* __restrict__ nvv,
    const float* __restrict__ gamma, const float* __restrict__ beta,
    unsigned short* __restrict__ outb)
{
    __shared__ float sbs[32];
    __shared__ float sums[32];
    compute_sb(stats, nvv, gamma, beta, sbs, sums);

    int b = blockIdx.y;
    int r = blockIdx.x * 256 + threadIdx.x;
    if (r > NN) return;
    int cnt = nvv[b];
    uint4 lo = make_uint4(0, 0, 0, 0), hi = lo;
    if (r < cnt) {
        const uint4* ip = (const uint4*)(in + ((size_t)b * NN + r) * 16);
        uint4 xl = ip[0], xh = ip[1];
        float y[16];
        #pragma unroll
        for (int c = 0; c < 16; c++) {
            unsigned u = (c < 8) ? ((const unsigned*)&xl)[c >> 1]
                                 : ((const unsigned*)&xh)[(c - 8) >> 1];
            unsigned short sv = (c & 1) ? (unsigned short)(u >> 16)
                                        : (unsigned short)(u & 0xffff);
            y[c] = fmaxf(fmaf(bf2f(sv), sbs[c], sbs[16 + c]), 0.f);
        }
        lo = make_uint4(pk2(y[0], y[1]), pk2(y[2], y[3]), pk2(y[4], y[5]), pk2(y[6], y[7]));
        hi = make_uint4(pk2(y[8], y[9]), pk2(y[10], y[11]), pk2(y[12], y[13]), pk2(y[14], y[15]));
    }
    unsigned short* op = outb + ((size_t)b * NS + r) * 16;
    *(uint4*)op       = lo;
    *(uint4*)(op + 8) = hi;
}

// ---------------------------------------------------------------------------
// K7: final BN2+ReLU, n-indexed: coalesced HBM writes, scattered L2/L3 reads.
// ---------------------------------------------------------------------------
__global__ __launch_bounds__(256) void final_out_kernel(
    const unsigned short* __restrict__ in,     // (B,NN,16) bf16 pre-BN sorted
    const int* __restrict__ rinv,              // (B,NN) n -> rank
    const float* __restrict__ stats, const int* __restrict__ nvv,
    const float* __restrict__ gamma, const float* __restrict__ beta,
    float* __restrict__ out)
{
    __shared__ float sbs[32];
    __shared__ float sums[32];
    compute_sb(stats, nvv, gamma, beta, sbs, sums);

    int b = blockIdx.y;
    int n = blockIdx.x * 256 + threadIdx.x;
    int cnt = nvv[b];
    float4* op = (float4*)(out + ((size_t)b * NN + n) * 16);
    if (n < cnt) {
        int r = rinv[(size_t)b * NN + n];
        const uint4* ip = (const uint4*)(in + ((size_t)b * NN + r) * 16);
        uint4 xl = ip[0], xh = ip[1];
        float y[16];
        #pragma unroll
        for (int c = 0; c < 16; c++) {
            unsigned u = (c < 8) ? ((const unsigned*)&xl)[c >> 1]
                                 : ((const unsigned*)&xh)[(c - 8) >> 1];
            unsigned short sv = (c & 1) ? (unsigned short)(u >> 16)
                                        : (unsigned short)(u & 0xffff);
            y[c] = fmaxf(fmaf(bf2f(sv), sbs[c], sbs[16 + c]), 0.f);
        }
        op[0] = make_float4(y[0],  y[1],  y[2],  y[3]);
        op[1] = make_float4(y[4],  y[5],  y[6],  y[7]);
        op[2] = make_float4(y[8],  y[9],  y[10], y[11]);
        op[3] = make_float4(y[12], y[13], y[14], y[15]);
    } else {
        float4 z = make_float4(0.f, 0.f, 0.f, 0.f);
        op[0] = z; op[1] = z; op[2] = z; op[3] = z;
    }
}

// ---------------------------------------------------------------------------
extern "C" void kernel_launch(void* const* d_in, const int* in_sizes, int n_in,
                              void* d_out, int out_size, void* d_ws, size_t ws_size,
                              hipStream_t stream)
{
    const float* feats  = (const float*)d_in[0];
    const int*   xyz    = (const int*)d_in[1];
    const int*   nvv    = (const int*)d_in[2];
    const float* w0     = (const float*)d_in[3];
    const float* w1     = (const float*)d_in[4];
    const float* nw0    = (const float*)d_in[5];
    const float* nw1    = (const float*)d_in[6];
    const float* gamma0 = (const float*)d_in[7];
    const float* beta0  = (const float*)d_in[8];
    const float* gamma1 = (const float*)d_in[9];
    const float* beta1  = (const float*)d_in[10];
    float* out = (float*)d_out;

    char* ws = (char*)d_ws;
    float*    stats1  = (float*)ws;          ws += 16 * 32 * 4;                // 2 KB (zeroed by K12)
    float*    stats2  = (float*)ws;          ws += 16 * 32 * 4;                // 2 KB (zeroed by K12)
    int2*     mwb     = (int2*)ws;           ws += (size_t)NB * NW * 8;        // 512 KB
    int2*     srow    = (int2*)ws;           ws += (size_t)NB * NN * 8;        // 4 MB
    unsigned short* sfA = (unsigned short*)ws; ws += (size_t)NB * NS * 16 * 2; // 16.8 MB
    unsigned short* sfB = (unsigned short*)ws; ws += (size_t)NB * NS * 16 * 2; // 16.8 MB
    unsigned short* bufPre = (unsigned short*)ws; ws += (size_t)NB * NN * 16 * 2; // 16 MB
    unsigned short* wfr = (unsigned short*)ws; ws += (size_t)2 * 14 * 512 * 2; // 28 KB
    int*      rinv    = (int*)ws;            ws += (size_t)NB * NN * 4;        // 2 MB

    // K12: mask(LDS)+scan+weight-pack+stats-zero (replaces memset+K1+K2)
    mask_scan_kernel<<<NB, 1024, 0, stream>>>(
        xyz, nvv, mwb, w0, w1, wfr, stats1, stats2);

    dim3 gridBN(NN / 256, NB);
    perm_gather_kernel<<<gridBN, 256, 0, stream>>>(xyz, nvv, mwb, feats, srow, sfA, rinv);

    // Layer 1: sorted bf16 in -> sorted bf16 (pre-BN) out + stats1
    conv_mfma_kernel<<<NBLKC, 256, 0, stream>>>(
        sfA, srow, nvv, mwb, wfr, nw0, bufPre, stats1);
    bnrelu_sorted_kernel<<<dim3(NN / 256 + 1, NB), 256, 0, stream>>>(
        bufPre, stats1, nvv, gamma0, beta0, sfB);

    // Layer 2: sorted bf16 in -> sorted bf16 (pre-BN) out + stats2
    conv_mfma_kernel<<<NBLKC, 256, 0, stream>>>(
        sfB, srow, nvv, mwb, wfr + 14 * 512, nw1, bufPre, stats2);

    // Final: BN2+ReLU, coalesced n-order writes, zero invalid rows
    final_out_kernel<<<dim3(NN / 256, NB), 256, 0, stream>>>(
        bufPre, rinv, stats2, nvv, gamma1, beta1, out);
}

// Round 10
// 231.971 us; speedup vs baseline: 9.1312x; 1.0118x over previous
//
#include <hip/hip_runtime.h>
#include <cstdint>
#include <cstddef>

#define NB 8
#define NN 65536
#define NS (NN + 16)         // sorted-buffer row stride (row NN = zero sentinel)
#define GG 64
#define GG3 (GG*GG*GG)
#define NW (GG3/32)          // 8192 mask words per batch
#define NBLKC 2048           // conv blocks (8/CU resident at 64 VGPR + 16KB LDS)
#define EPSC 1e-3f

typedef __bf16 bf16x8 __attribute__((ext_vector_type(8)));
typedef float  f32x4  __attribute__((ext_vector_type(4)));

__device__ __forceinline__ unsigned short f2bf(float f) {
    unsigned u = __builtin_bit_cast(unsigned, f);
    unsigned r = (u + 0x7fffu + ((u >> 16) & 1u)) >> 16;
    return (unsigned short)r;
}
__device__ __forceinline__ unsigned pk2(float a, float b) {
    return (unsigned)f2bf(a) | ((unsigned)f2bf(b) << 16);
}
__device__ __forceinline__ float bf2f(unsigned short s) {
    return __builtin_bit_cast(float, (unsigned)s << 16);
}

__device__ __forceinline__ int site_rank2(const int2* __restrict__ mwb, int lin) {
    int2 mw = mwb[lin >> 5];
    uint32_t w = (uint32_t)mw.x;
    uint32_t bit = 1u << (lin & 31);
    if (!(w & bit)) return -1;
    return mw.y + __popc(w & (bit - 1u));
}

// ---------------------------------------------------------------------------
// K12: fused mask-build (LDS atomics) + scan -> mwb. One block per batch.
// Round-10 rework: wave-shuffle scan (4 barriers vs 22), thread-major word
// ordering (conflict-free LDS reads; rank order is a different but
// consistent bijection -- all consumers derive ranks solely from mwb),
// atomic loop bounded by cnt. Also: weight packing (blocks 0,1), stats zero.
// ---------------------------------------------------------------------------
__global__ __launch_bounds__(1024) void mask_scan_kernel(
    const int* __restrict__ xyz, const int* __restrict__ nvv,
    int2* __restrict__ mwb,
    const float* __restrict__ w0, const float* __restrict__ w1,
    unsigned short* __restrict__ wf,
    float* __restrict__ stats1, float* __restrict__ stats2)
{
    __shared__ uint32_t lmask[NW];     // 32 KB occupancy bitmap for this batch
    __shared__ int wsum[16];
    __shared__ int woff[16];
    int b = blockIdx.x;
    int t = threadIdx.x;
    int lane = t & 63, wv = t >> 6;    // 16 waves

    #pragma unroll
    for (int i = 0; i < NW / 1024; i++) lmask[t + i * 1024] = 0u;
    if (b == 0 && t < 512) { stats1[t] = 0.f; stats2[t] = 0.f; }
    __syncthreads();

    int cnt = nvv[b];
    const int* xb = xyz + (size_t)b * NN * 3;
    #pragma unroll 8
    for (int n = t; n < cnt; n += 1024) {
        const int* cp = xb + n * 3;
        int lin = cp[0] * (GG * GG) + cp[1] * GG + cp[2];
        atomicOr(&lmask[lin >> 5], 1u << (lin & 31));
    }
    __syncthreads();

    // thread-major word ownership: thread t owns words i*1024+t (i=0..7)
    uint32_t wvv[8];
    int cnts[8];
    int local = 0;
    #pragma unroll
    for (int i = 0; i < 8; i++) {
        wvv[i] = lmask[i * 1024 + t];      // stride-4B: conflict-free
        cnts[i] = __popc(wvv[i]);
        local += cnts[i];
    }

    // wave-level inclusive scan (6 shfl steps, no barrier)
    int inc = local;
    #pragma unroll
    for (int d = 1; d < 64; d <<= 1) {
        int vtmp = __shfl_up(inc, d, 64);
        if (lane >= d) inc += vtmp;
    }
    if (lane == 63) wsum[wv] = inc;
    __syncthreads();
    if (t < 16) {
        int s = wsum[t];
        int e = s;
        #pragma unroll
        for (int d = 1; d < 16; d <<= 1) {
            int vtmp = __shfl_up(e, d, 16);
            if ((t & 15) >= d) e += vtmp;
        }
        woff[t] = e - s;   // exclusive wave offset
    }
    __syncthreads();

    int base = woff[wv] + (inc - local);   // exclusive prefix for this thread
    int2* wb = mwb + (size_t)b * NW;
    #pragma unroll
    for (int i = 0; i < 8; i++) {
        wb[i * 1024 + t] = make_int2((int)wvv[i], base);
        base += cnts[i];
    }

    // weight packing (blocks 0,1)
    if (b < 2) {
        const float* w = b ? w1 : w0;
        unsigned short* o = wf + b * 14 * 512;
        for (int idx = t; idx < 14 * 512; idx += 1024) {
            int i = idx >> 9;
            int rem = idx & 511;
            int L = rem >> 3, j = rem & 7;
            int quad = L >> 4, nn = L & 15;
            int off = 2 * i + (quad >> 1);
            int c = ((quad & 1) << 3) + j;
            float v = (off < 27) ? w[(off * 16 + c) * 16 + nn] : 0.f;
            o[idx] = f2bf(v);
        }
    }
}

// ---------------------------------------------------------------------------
// K3: permutation + gather feats (fp32) into rank-sorted bf16 rows.
// Also writes rinv[n] = rank (for coalesced final output pass).
// ---------------------------------------------------------------------------
__global__ __launch_bounds__(256) void perm_gather_kernel(
    const int* __restrict__ xyz, const int* __restrict__ nvv,
    const int2* __restrict__ mwb,
    const float* __restrict__ feats,
    int2* __restrict__ srow,
    unsigned short* __restrict__ sfeats,
    int* __restrict__ rinv)
{
    int b = blockIdx.y;
    int n = blockIdx.x * 256 + threadIdx.x;
    int cnt = nvv[b];
    unsigned short* sfb = sfeats + (size_t)b * NS * 16;
    if (blockIdx.x == 0 && threadIdx.x < 16)
        sfb[(size_t)NN * 16 + threadIdx.x] = 0;     // sentinel row
    if (n < cnt) {
        const int* cp = xyz + ((size_t)b * NN + n) * 3;
        int lin = cp[0] * (GG * GG) + cp[1] * GG + cp[2];
        int r = site_rank2(mwb + (size_t)b * NW, lin);
        srow[(size_t)b * NN + r] = make_int2(lin, n);
        rinv[(size_t)b * NN + n] = r;
        const float4* fp = (const float4*)(feats + ((size_t)b * NN + n) * 16);
        float4 f0 = fp[0], f1 = fp[1], f2 = fp[2], f3 = fp[3];
        uint4 lo = make_uint4(pk2(f0.x, f0.y), pk2(f0.z, f0.w),
                              pk2(f1.x, f1.y), pk2(f1.z, f1.w));
        uint4 hi = make_uint4(pk2(f2.x, f2.y), pk2(f2.z, f2.w),
                              pk2(f3.x, f3.y), pk2(f3.z, f3.w));
        *(uint4*)(sfb + (size_t)r * 16)     = lo;
        *(uint4*)(sfb + (size_t)r * 16 + 8) = hi;
    } else {
        uint4 z = make_uint4(0, 0, 0, 0);
        *(uint4*)(sfb + (size_t)n * 16)     = z;
        *(uint4*)(sfb + (size_t)n * 16 + 8) = z;
    }
}

// ---------------------------------------------------------------------------
// K4/K6: MFMA sparse conv, round-6 body verbatim (64 VGPR, spill-free),
// XCD-locality tile mapping (batch = blockIdx&7 -> per-XCD L2 residency;
// confirmed by FETCH_SIZE 8.9MB vs 23.9MB non-mapped).
// ---------------------------------------------------------------------------
__global__ __launch_bounds__(256, 4) void conv_mfma_kernel(
    const unsigned short* __restrict__ sfeats,  // (B,NS,16) bf16 rank-sorted
    const int2*     __restrict__ srow,          // (B,NN) rank -> {lin, n}
    const int*      __restrict__ nvv,
    const int2*     __restrict__ mwb,           // (B,NW) {mask word, base}
    const unsigned short* __restrict__ wfrag,   // 14*512 bf16 B-frags
    const float*    __restrict__ nw,            // (27,)
    unsigned short* __restrict__ outbuf,        // (B,NN,16) bf16 pre-BN sorted
    float*          __restrict__ stats)         // [16][32] striped accumulators
{
    int lane = threadIdx.x & 63;
    int wv = threadIdx.x >> 6;
    int m = lane & 15, quad = lane >> 4;       // compute-phase layout
    int v = lane & 31, h = lane >> 5;          // rank-phase layout

    // XCD-aware mapping: batch = XCD slot; 256 blocks x 4 waves per batch
    int b    = blockIdx.x & 7;                 // batch == XCD (heuristic)
    int widb = (blockIdx.x >> 3) * 4 + wv;     // wave-in-batch [0, 1024)

    __shared__ int   jj[4][32][29];            // stride 29: conflict-free-ish
    __shared__ float rrl[4][32];
    __shared__ float red[4][32];
    __shared__ float lnw[27];

    if (threadIdx.x < 27) lnw[threadIdx.x] = nw[threadIdx.x];

    // B-fragments: loaded once per wave, held in registers
    bf16x8 bfr[14];
    #pragma unroll
    for (int i = 0; i < 14; i++)
        bfr[i] = *(const bf16x8*)(wfrag + i * 512 + lane * 8);
    __syncthreads();

    float psum = 0.f, psq = 0.f;
    int coff = (quad & 1) << 3;

    // wave-uniform per-batch bases (SGPR-resident)
    int cnt = nvv[b];
    const int2* mb = mwb + (size_t)b * NW;
    const unsigned short* fb = sfeats + (size_t)b * NS * 16;
    const int2* sr = srow + (size_t)b * NN;

    #pragma unroll 1
    for (int k = 0; k < 2; k++) {
        int r0 = (widb + k * 1024) << 5;       // 32 ranks per pair-tile
        if (r0 >= cnt) continue;

        // ---- rank phase: slot = (voxel v, column c = 2t + h), c in [0,9) ----
        int Rv = r0 + v;
        bool vld = Rv < cnt;
        int lin = vld ? sr[Rv].x : 0;
        int x = lin >> 12, y = (lin >> 6) & 63, z = lin & 63;
        int zb = z & 31;
        float nc = 0.f;
        #pragma unroll
        for (int t = 0; t < 5; t++) {
            int c = 2 * t + h;
            bool cok = c < 9;
            int cc = cok ? c : 0;
            int dx = cc / 3 - 1, dy = cc % 3 - 1;
            int nx = x + dx, ny = y + dy;
            bool colok = cok & ((unsigned)nx < 64u) & ((unsigned)ny < 64u);
            int wdi = colok ? (((nx << 12) + (ny << 6) + z) >> 5) : 0;

            int2 mw = make_int2(0, 0);
            if (vld & colok) mw = mb[wdi];
            // rare 2nd word when z-1/z+1 crosses the 32-bit boundary
            bool need2 = vld & colok & (((zb == 0) & (z > 0)) | ((zb == 31) & (z < 63)));
            int w2 = wdi + ((zb == 0) ? -1 : 1);
            int2 mw2 = make_int2(0, 0);
            if (need2) mw2 = mb[w2];

            #pragma unroll
            for (int dz = -1; dz <= 1; dz++) {
                int zz = z + dz;
                bool zok = (unsigned)zz < 64u;
                bool same = (dz == 0) | ((dz < 0) ? (zb != 0) : (zb != 31));
                int2 word = same ? mw : mw2;
                int bb = zz & 31;
                uint32_t wm = (uint32_t)word.x;
                bool hit = vld & colok & zok & ((wm >> bb) & 1u);
                int rnk = word.y + __popc(wm & ((1u << bb) - 1u));
                int off = cc * 3 + dz + 1;
                int jv = hit ? rnk : NN;
                if (cok) {
                    jj[wv][v][off] = jv;
                    nc += hit ? lnw[off] : 0.f;
                }
            }
        }
        nc += __shfl_xor(nc, 32, 64);
        if (lane < 32) rrl[wv][v] = 1.f / (1.f + fabsf(nc));

        // ---- compute phase: 28 gathers + 28 MFMAs (two independent chains) ----
        f32x4 acc0 = {0.f, 0.f, 0.f, 0.f};
        f32x4 acc1 = {0.f, 0.f, 0.f, 0.f};
        #pragma unroll
        for (int i = 0; i < 14; i++) {
            int off = 2 * i + (quad >> 1);
            int idx = off < 27 ? off : 28;
            int j0 = jj[wv][m][idx];      j0 = (off < 27) ? j0 : NN;
            int j1 = jj[wv][m + 16][idx]; j1 = (off < 27) ? j1 : NN;
            bf16x8 a0 = *(const bf16x8*)(fb + (size_t)j0 * 16 + coff);
            bf16x8 a1 = *(const bf16x8*)(fb + (size_t)j1 * 16 + coff);
            acc0 = __builtin_amdgcn_mfma_f32_16x16x32_bf16(a0, bfr[i], acc0, 0, 0, 0);
            acc1 = __builtin_amdgcn_mfma_f32_16x16x32_bf16(a1, bfr[i], acc1, 0, 0, 0);
        }

        // ---- epilogue: D[row=quad*4+r][ch=m], both halves ----
        #pragma unroll
        for (int hh = 0; hh < 2; hh++) {
            int rbase = r0 + (hh << 4);
            #pragma unroll
            for (int r4 = 0; r4 < 4; r4++) {
                int row = (quad << 2) + r4;
                float tval = (hh ? acc1[r4] : acc0[r4]) * rrl[wv][(hh << 4) + row];
                psum += tval; psq += tval * tval;
                int Rr = rbase + row;
                if (Rr < cnt)
                    outbuf[((size_t)b * NN + Rr) * 16 + m] = f2bf(tval);
            }
        }
    }

    // ---- BN partial stats: block reduce, striped atomics ----
    psum += __shfl_xor(psum, 16, 64); psum += __shfl_xor(psum, 32, 64);
    psq  += __shfl_xor(psq, 16, 64);  psq  += __shfl_xor(psq, 32, 64);
    if (lane < 16) { red[wv][lane] = psum; red[wv][16 + lane] = psq; }
    __syncthreads();
    if (threadIdx.x < 32) {
        float vv = red[0][threadIdx.x] + red[1][threadIdx.x] +
                   red[2][threadIdx.x] + red[3][threadIdx.x];
        atomicAdd(&stats[(blockIdx.x & 15) * 32 + threadIdx.x], vv);
    }
}

// ---------------------------------------------------------------------------
// shared helper: derive per-channel scale/bias from striped stats into LDS
// ---------------------------------------------------------------------------
__device__ __forceinline__ void compute_sb(
    const float* __restrict__ stats, const int* __restrict__ nvv,
    const float* __restrict__ gamma, const float* __restrict__ beta,
    float* sbs /*LDS[32]*/, float* sums /*LDS[32]*/)
{
    int tid = threadIdx.x;
    if (tid < 32) {
        float v = 0.f;
        #pragma unroll
        for (int s = 0; s < 16; s++) v += stats[s * 32 + tid];
        sums[tid] = v;
    }
    __syncthreads();
    if (tid < 16) {
        float cnt = 0.f;
        #pragma unroll
        for (int b = 0; b < NB; b++) cnt += (float)nvv[b];
        float mean = sums[tid] / cnt;
        float var  = fmaxf(sums[16 + tid] / cnt - mean * mean, 0.f);
        float scv = gamma[tid] * rsqrtf(var + EPSC);
        sbs[tid]      = scv;
        sbs[16 + tid] = beta[tid] - mean * scv;
    }
    __syncthreads();
}

// ---------------------------------------------------------------------------
// K5: BN1+ReLU on sorted bf16 -> sorted bf16 (rows [cnt,NN] zeroed); sb fused
// ---------------------------------------------------------------------------
__global__ __launch_bounds__(256) void bnrelu_sorted_kernel(
    const unsigned short* __restrict__ in, const float* __restrict__ stats,
    const int* __restrict__ nvv,
    const float* __restrict__ gamma, const float* __restrict__ beta,
    unsigned short* __restrict__ outb)
{
    __shared__ float sbs[32];
    __shared__ float sums[32];
    compute_sb(stats, nvv, gamma, beta, sbs, sums);

    int b = blockIdx.y;
    int r = blockIdx.x * 256 + threadIdx.x;
    if (r > NN) return;
    int cnt = nvv[b];
    uint4 lo = make_uint4(0, 0, 0, 0), hi = lo;
    if (r < cnt) {
        const uint4* ip = (const uint4*)(in + ((size_t)b * NN + r) * 16);
        uint4 xl = ip[0], xh = ip[1];
        float y[16];
        #pragma unroll
        for (int c = 0; c < 16; c++) {
            unsigned u = (c < 8) ? ((const unsigned*)&xl)[c >> 1]
                                 : ((const unsigned*)&xh)[(c - 8) >> 1];
            unsigned short sv = (c & 1) ? (unsigned short)(u >> 16)
                                        : (unsigned short)(u & 0xffff);
            y[c] = fmaxf(fmaf(bf2f(sv), sbs[c], sbs[16 + c]), 0.f);
        }
        lo = make_uint4(pk2(y[0], y[1]), pk2(y[2], y[3]), pk2(y[4], y[5]), pk2(y[6], y[7]));
        hi = make_uint4(pk2(y[8], y[9]), pk2(y[10], y[11]), pk2(y[12], y[13]), pk2(y[14], y[15]));
    }
    unsigned short* op = outb + ((size_t)b * NS + r) * 16;
    *(uint4*)op       = lo;
    *(uint4*)(op + 8) = hi;
}

// ---------------------------------------------------------------------------
// K7: final BN2+ReLU, n-indexed: coalesced HBM writes, scattered L2/L3 reads.
// ---------------------------------------------------------------------------
__global__ __launch_bounds__(256) void final_out_kernel(
    const unsigned short* __restrict__ in,     // (B,NN,16) bf16 pre-BN sorted
    const int* __restrict__ rinv,              // (B,NN) n -> rank
    const float* __restrict__ stats, const int* __restrict__ nvv,
    const float* __restrict__ gamma, const float* __restrict__ beta,
    float* __restrict__ out)
{
    __shared__ float sbs[32];
    __shared__ float sums[32];
    compute_sb(stats, nvv, gamma, beta, sbs, sums);

    int b = blockIdx.y;
    int n = blockIdx.x * 256 + threadIdx.x;
    int cnt = nvv[b];
    float4* op = (float4*)(out + ((size_t)b * NN + n) * 16);
    if (n < cnt) {
        int r = rinv[(size_t)b * NN + n];
        const uint4* ip = (const uint4*)(in + ((size_t)b * NN + r) * 16);
        uint4 xl = ip[0], xh = ip[1];
        float y[16];
        #pragma unroll
        for (int c = 0; c < 16; c++) {
            unsigned u = (c < 8) ? ((const unsigned*)&xl)[c >> 1]
                                 : ((const unsigned*)&xh)[(c - 8) >> 1];
            unsigned short sv = (c & 1) ? (unsigned short)(u >> 16)
                                        : (unsigned short)(u & 0xffff);
            y[c] = fmaxf(fmaf(bf2f(sv), sbs[c], sbs[16 + c]), 0.f);
        }
        op[0] = make_float4(y[0],  y[1],  y[2],  y[3]);
        op[1] = make_float4(y[4],  y[5],  y[6],  y[7]);
        op[2] = make_float4(y[8],  y[9],  y[10], y[11]);
        op[3] = make_float4(y[12], y[13], y[14], y[15]);
    } else {
        float4 z = make_float4(0.f, 0.f, 0.f, 0.f);
        op[0] = z; op[1] = z; op[2] = z; op[3] = z;
    }
}

// ---------------------------------------------------------------------------
extern "C" void kernel_launch(void* const* d_in, const int* in_sizes, int n_in,
                              void* d_out, int out_size, void* d_ws, size_t ws_size,
                              hipStream_t stream)
{
    const float* feats  = (const float*)d_in[0];
    const int*   xyz    = (const int*)d_in[1];
    const int*   nvv    = (const int*)d_in[2];
    const float* w0     = (const float*)d_in[3];
    const float* w1     = (const float*)d_in[4];
    const float* nw0    = (const float*)d_in[5];
    const float* nw1    = (const float*)d_in[6];
    const float* gamma0 = (const float*)d_in[7];
    const float* beta0  = (const float*)d_in[8];
    const float* gamma1 = (const float*)d_in[9];
    const float* beta1  = (const float*)d_in[10];
    float* out = (float*)d_out;

    char* ws = (char*)d_ws;
    float*    stats1  = (float*)ws;          ws += 16 * 32 * 4;                // 2 KB (zeroed by K12)
    float*    stats2  = (float*)ws;          ws += 16 * 32 * 4;                // 2 KB (zeroed by K12)
    int2*     mwb     = (int2*)ws;           ws += (size_t)NB * NW * 8;        // 512 KB
    int2*     srow    = (int2*)ws;           ws += (size_t)NB * NN * 8;        // 4 MB
    unsigned short* sfA = (unsigned short*)ws; ws += (size_t)NB * NS * 16 * 2; // 16.8 MB
    unsigned short* sfB = (unsigned short*)ws; ws += (size_t)NB * NS * 16 * 2; // 16.8 MB
    unsigned short* bufPre = (unsigned short*)ws; ws += (size_t)NB * NN * 16 * 2; // 16 MB
    unsigned short* wfr = (unsigned short*)ws; ws += (size_t)2 * 14 * 512 * 2; // 28 KB
    int*      rinv    = (int*)ws;            ws += (size_t)NB * NN * 4;        // 2 MB

    // K12: mask(LDS)+scan+weight-pack+stats-zero (replaces memset+K1+K2)
    mask_scan_kernel<<<NB, 1024, 0, stream>>>(
        xyz, nvv, mwb, w0, w1, wfr, stats1, stats2);

    dim3 gridBN(NN / 256, NB);
    perm_gather_kernel<<<gridBN, 256, 0, stream>>>(xyz, nvv, mwb, feats, srow, sfA, rinv);

    // Layer 1: sorted bf16 in -> sorted bf16 (pre-BN) out + stats1
    conv_mfma_kernel<<<NBLKC, 256, 0, stream>>>(
        sfA, srow, nvv, mwb, wfr, nw0, bufPre, stats1);
    bnrelu_sorted_kernel<<<dim3(NN / 256 + 1, NB), 256, 0, stream>>>(
        bufPre, stats1, nvv, gamma0, beta0, sfB);

    // Layer 2: sorted bf16 in -> sorted bf16 (pre-BN) out + stats2
    conv_mfma_kernel<<<NBLKC, 256, 0, stream>>>(
        sfB, srow, nvv, mwb, wfr + 14 * 512, nw1, bufPre, stats2);

    // Final: BN2+ReLU, coalesced n-order writes, zero invalid rows
    final_out_kernel<<<dim3(NN / 256, NB), 256, 0, stream>>>(
        bufPre, rinv, stats2, nvv, gamma1, beta1, out);
}

// Round 11
// 229.228 us; speedup vs baseline: 9.2405x; 1.0120x over previous
//
#include <hip/hip_runtime.h>
#include <cstdint>
#include <cstddef>

#define NB 8
#define NN 65536
#define NS (NN + 16)         // sorted-buffer row stride (row NN = zero sentinel)
#define GG 64
#define GG3 (GG*GG*GG)
#define NW (GG3/32)          // 8192 mask words per batch
#define NBLKC 2048           // conv blocks (8/CU resident at 64 VGPR + 16KB LDS)
#define EPSC 1e-3f

typedef __bf16 bf16x8 __attribute__((ext_vector_type(8)));
typedef float  f32x4  __attribute__((ext_vector_type(4)));

__device__ __forceinline__ unsigned short f2bf(float f) {
    unsigned u = __builtin_bit_cast(unsigned, f);
    unsigned r = (u + 0x7fffu + ((u >> 16) & 1u)) >> 16;
    return (unsigned short)r;
}
__device__ __forceinline__ unsigned pk2(float a, float b) {
    return (unsigned)f2bf(a) | ((unsigned)f2bf(b) << 16);
}
__device__ __forceinline__ float bf2f(unsigned short s) {
    return __builtin_bit_cast(float, (unsigned)s << 16);
}

__device__ __forceinline__ int site_rank2(const int2* __restrict__ mwb, int lin) {
    int2 mw = mwb[lin >> 5];
    uint32_t w = (uint32_t)mw.x;
    uint32_t bit = 1u << (lin & 31);
    if (!(w & bit)) return -1;
    return mw.y + __popc(w & (bit - 1u));
}

// ---------------------------------------------------------------------------
// K12: fused mask-build (LDS atomics) + wave-shuffle scan -> mwb.
// One block per batch; thread-major word ordering (conflict-free).
// Also: weight packing (blocks 0,1), stats zeroing (block 0).
// ---------------------------------------------------------------------------
__global__ __launch_bounds__(1024) void mask_scan_kernel(
    const int* __restrict__ xyz, const int* __restrict__ nvv,
    int2* __restrict__ mwb,
    const float* __restrict__ w0, const float* __restrict__ w1,
    unsigned short* __restrict__ wf,
    float* __restrict__ stats1, float* __restrict__ stats2)
{
    __shared__ uint32_t lmask[NW];     // 32 KB occupancy bitmap for this batch
    __shared__ int wsum[16];
    __shared__ int woff[16];
    int b = blockIdx.x;
    int t = threadIdx.x;
    int lane = t & 63, wv = t >> 6;    // 16 waves

    #pragma unroll
    for (int i = 0; i < NW / 1024; i++) lmask[t + i * 1024] = 0u;
    if (b == 0 && t < 512) { stats1[t] = 0.f; stats2[t] = 0.f; }
    __syncthreads();

    int cnt = nvv[b];
    const int* xb = xyz + (size_t)b * NN * 3;
    #pragma unroll 8
    for (int n = t; n < cnt; n += 1024) {
        const int* cp = xb + n * 3;
        int lin = cp[0] * (GG * GG) + cp[1] * GG + cp[2];
        atomicOr(&lmask[lin >> 5], 1u << (lin & 31));
    }
    __syncthreads();

    // thread-major word ownership: thread t owns words i*1024+t (i=0..7)
    uint32_t wvv[8];
    int cnts[8];
    int local = 0;
    #pragma unroll
    for (int i = 0; i < 8; i++) {
        wvv[i] = lmask[i * 1024 + t];      // stride-4B: conflict-free
        cnts[i] = __popc(wvv[i]);
        local += cnts[i];
    }

    // wave-level inclusive scan (6 shfl steps, no barrier)
    int inc = local;
    #pragma unroll
    for (int d = 1; d < 64; d <<= 1) {
        int vtmp = __shfl_up(inc, d, 64);
        if (lane >= d) inc += vtmp;
    }
    if (lane == 63) wsum[wv] = inc;
    __syncthreads();
    if (t < 16) {
        int s = wsum[t];
        int e = s;
        #pragma unroll
        for (int d = 1; d < 16; d <<= 1) {
            int vtmp = __shfl_up(e, d, 16);
            if ((t & 15) >= d) e += vtmp;
        }
        woff[t] = e - s;   // exclusive wave offset
    }
    __syncthreads();

    int base = woff[wv] + (inc - local);   // exclusive prefix for this thread
    int2* wb = mwb + (size_t)b * NW;
    #pragma unroll
    for (int i = 0; i < 8; i++) {
        wb[i * 1024 + t] = make_int2((int)wvv[i], base);
        base += cnts[i];
    }

    // weight packing (blocks 0,1)
    if (b < 2) {
        const float* w = b ? w1 : w0;
        unsigned short* o = wf + b * 14 * 512;
        for (int idx = t; idx < 14 * 512; idx += 1024) {
            int i = idx >> 9;
            int rem = idx & 511;
            int L = rem >> 3, j = rem & 7;
            int quad = L >> 4, nn = L & 15;
            int off = 2 * i + (quad >> 1);
            int c = ((quad & 1) << 3) + j;
            float v = (off < 27) ? w[(off * 16 + c) * 16 + nn] : 0.f;
            o[idx] = f2bf(v);
        }
    }
}

// ---------------------------------------------------------------------------
// K3: permutation + gather feats (fp32) into rank-sorted bf16 rows.
// Rows [cnt,NN) are never read by conv (all ranks < cnt; misses hit the
// sentinel row NN) -> no zero-fill for them. Writes rinv[n] = rank.
// ---------------------------------------------------------------------------
__global__ __launch_bounds__(256) void perm_gather_kernel(
    const int* __restrict__ xyz, const int* __restrict__ nvv,
    const int2* __restrict__ mwb,
    const float* __restrict__ feats,
    int2* __restrict__ srow,
    unsigned short* __restrict__ sfeats,
    int* __restrict__ rinv)
{
    int b = blockIdx.y;
    int n = blockIdx.x * 256 + threadIdx.x;
    int cnt = nvv[b];
    unsigned short* sfb = sfeats + (size_t)b * NS * 16;
    if (blockIdx.x == 0 && threadIdx.x < 16)
        sfb[(size_t)NN * 16 + threadIdx.x] = 0;     // sentinel row
    if (n < cnt) {
        const int* cp = xyz + ((size_t)b * NN + n) * 3;
        int lin = cp[0] * (GG * GG) + cp[1] * GG + cp[2];
        int r = site_rank2(mwb + (size_t)b * NW, lin);
        srow[(size_t)b * NN + r] = make_int2(lin, n);
        rinv[(size_t)b * NN + n] = r;
        const float4* fp = (const float4*)(feats + ((size_t)b * NN + n) * 16);
        float4 f0 = fp[0], f1 = fp[1], f2 = fp[2], f3 = fp[3];
        uint4 lo = make_uint4(pk2(f0.x, f0.y), pk2(f0.z, f0.w),
                              pk2(f1.x, f1.y), pk2(f1.z, f1.w));
        uint4 hi = make_uint4(pk2(f2.x, f2.y), pk2(f2.z, f2.w),
                              pk2(f3.x, f3.y), pk2(f3.z, f3.w));
        *(uint4*)(sfb + (size_t)r * 16)     = lo;
        *(uint4*)(sfb + (size_t)r * 16 + 8) = hi;
    }
}

// ---------------------------------------------------------------------------
// K4/K6: MFMA sparse conv, round-6 body (64 VGPR, spill-free), XCD-locality
// tile mapping (batch = blockIdx&7 -> per-XCD L2 residency; FETCH 8.9MB vs
// 23.9MB non-mapped). New: tile-1 srow prefetch issued during tile 0.
// ---------------------------------------------------------------------------
__global__ __launch_bounds__(256, 4) void conv_mfma_kernel(
    const unsigned short* __restrict__ sfeats,  // (B,NS,16) bf16 rank-sorted
    const int2*     __restrict__ srow,          // (B,NN) rank -> {lin, n}
    const int*      __restrict__ nvv,
    const int2*     __restrict__ mwb,           // (B,NW) {mask word, base}
    const unsigned short* __restrict__ wfrag,   // 14*512 bf16 B-frags
    const float*    __restrict__ nw,            // (27,)
    unsigned short* __restrict__ outbuf,        // (B,NN,16) bf16 pre-BN sorted
    float*          __restrict__ stats)         // [16][32] striped accumulators
{
    int lane = threadIdx.x & 63;
    int wv = threadIdx.x >> 6;
    int m = lane & 15, quad = lane >> 4;       // compute-phase layout
    int v = lane & 31, h = lane >> 5;          // rank-phase layout

    // XCD-aware mapping: batch = XCD slot; 256 blocks x 4 waves per batch
    int b    = blockIdx.x & 7;                 // batch == XCD (heuristic)
    int widb = (blockIdx.x >> 3) * 4 + wv;     // wave-in-batch [0, 1024)

    __shared__ int   jj[4][32][29];            // stride 29: conflict-free-ish
    __shared__ float rrl[4][32];
    __shared__ float red[4][32];
    __shared__ float lnw[27];

    if (threadIdx.x < 27) lnw[threadIdx.x] = nw[threadIdx.x];

    // B-fragments: loaded once per wave, held in registers
    bf16x8 bfr[14];
    #pragma unroll
    for (int i = 0; i < 14; i++)
        bfr[i] = *(const bf16x8*)(wfrag + i * 512 + lane * 8);
    __syncthreads();

    float psum = 0.f, psq = 0.f;
    int coff = (quad & 1) << 3;

    // wave-uniform per-batch bases (SGPR-resident)
    int cnt = nvv[b];
    const int2* mb = mwb + (size_t)b * NW;
    const unsigned short* fb = sfeats + (size_t)b * NS * 16;
    const int2* sr = srow + (size_t)b * NN;

    // prefetch tile 0's srow entry (tile 0 is always valid: r0 < 32768 <= cnt)
    int lin_nxt = sr[(widb << 5) + v].x;

    #pragma unroll 1
    for (int k = 0; k < 2; k++) {
        int r0 = (widb + k * 1024) << 5;       // 32 ranks per pair-tile
        int lin = lin_nxt;

        // issue tile-1's srow load now; hides under tile-0's rank+compute
        if (k == 0) {
            int Rv1 = r0 + (1024 << 5) + v;
            lin_nxt = (Rv1 < cnt) ? sr[Rv1].x : 0;
        }

        if (r0 >= cnt) continue;

        // ---- rank phase: slot = (voxel v, column c = 2t + h), c in [0,9) ----
        bool vld = (r0 + v) < cnt;
        if (!vld) lin = 0;
        int x = lin >> 12, y = (lin >> 6) & 63, z = lin & 63;
        int zb = z & 31;
        float nc = 0.f;
        #pragma unroll
        for (int t = 0; t < 5; t++) {
            int c = 2 * t + h;
            bool cok = c < 9;
            int cc = cok ? c : 0;
            int dx = cc / 3 - 1, dy = cc % 3 - 1;
            int nx = x + dx, ny = y + dy;
            bool colok = cok & ((unsigned)nx < 64u) & ((unsigned)ny < 64u);
            int wdi = colok ? (((nx << 12) + (ny << 6) + z) >> 5) : 0;

            int2 mw = make_int2(0, 0);
            if (vld & colok) mw = mb[wdi];
            // rare 2nd word when z-1/z+1 crosses the 32-bit boundary
            bool need2 = vld & colok & (((zb == 0) & (z > 0)) | ((zb == 31) & (z < 63)));
            int w2 = wdi + ((zb == 0) ? -1 : 1);
            int2 mw2 = make_int2(0, 0);
            if (need2) mw2 = mb[w2];

            #pragma unroll
            for (int dz = -1; dz <= 1; dz++) {
                int zz = z + dz;
                bool zok = (unsigned)zz < 64u;
                bool same = (dz == 0) | ((dz < 0) ? (zb != 0) : (zb != 31));
                int2 word = same ? mw : mw2;
                int bb = zz & 31;
                uint32_t wm = (uint32_t)word.x;
                bool hit = vld & colok & zok & ((wm >> bb) & 1u);
                int rnk = word.y + __popc(wm & ((1u << bb) - 1u));
                int off = cc * 3 + dz + 1;
                int jv = hit ? rnk : NN;
                if (cok) {
                    jj[wv][v][off] = jv;
                    nc += hit ? lnw[off] : 0.f;
                }
            }
        }
        nc += __shfl_xor(nc, 32, 64);
        if (lane < 32) rrl[wv][v] = 1.f / (1.f + fabsf(nc));

        // ---- compute phase: 28 gathers + 28 MFMAs (two independent chains) ----
        f32x4 acc0 = {0.f, 0.f, 0.f, 0.f};
        f32x4 acc1 = {0.f, 0.f, 0.f, 0.f};
        #pragma unroll
        for (int i = 0; i < 14; i++) {
            int off = 2 * i + (quad >> 1);
            int idx = off < 27 ? off : 28;
            int j0 = jj[wv][m][idx];      j0 = (off < 27) ? j0 : NN;
            int j1 = jj[wv][m + 16][idx]; j1 = (off < 27) ? j1 : NN;
            bf16x8 a0 = *(const bf16x8*)(fb + (size_t)j0 * 16 + coff);
            bf16x8 a1 = *(const bf16x8*)(fb + (size_t)j1 * 16 + coff);
            acc0 = __builtin_amdgcn_mfma_f32_16x16x32_bf16(a0, bfr[i], acc0, 0, 0, 0);
            acc1 = __builtin_amdgcn_mfma_f32_16x16x32_bf16(a1, bfr[i], acc1, 0, 0, 0);
        }

        // ---- epilogue: D[row=quad*4+r][ch=m], both halves ----
        #pragma unroll
        for (int hh = 0; hh < 2; hh++) {
            int rbase = r0 + (hh << 4);
            #pragma unroll
            for (int r4 = 0; r4 < 4; r4++) {
                int row = (quad << 2) + r4;
                float tval = (hh ? acc1[r4] : acc0[r4]) * rrl[wv][(hh << 4) + row];
                psum += tval; psq += tval * tval;
                int Rr = rbase + row;
                if (Rr < cnt)
                    outbuf[((size_t)b * NN + Rr) * 16 + m] = f2bf(tval);
            }
        }
    }

    // ---- BN partial stats: block reduce, striped atomics ----
    psum += __shfl_xor(psum, 16, 64); psum += __shfl_xor(psum, 32, 64);
    psq  += __shfl_xor(psq, 16, 64);  psq  += __shfl_xor(psq, 32, 64);
    if (lane < 16) { red[wv][lane] = psum; red[wv][16 + lane] = psq; }
    __syncthreads();
    if (threadIdx.x < 32) {
        float vv = red[0][threadIdx.x] + red[1][threadIdx.x] +
                   red[2][threadIdx.x] + red[3][threadIdx.x];
        atomicAdd(&stats[(blockIdx.x & 15) * 32 + threadIdx.x], vv);
    }
}

// ---------------------------------------------------------------------------
// shared helper: derive per-channel scale/bias from striped stats into LDS
// ---------------------------------------------------------------------------
__device__ __forceinline__ void compute_sb(
    const float* __restrict__ stats, const int* __restrict__ nvv,
    const float* __restrict__ gamma, const float* __restrict__ beta,
    float* sbs /*LDS[32]*/, float* sums /*LDS[32]*/)
{
    int tid = threadIdx.x;
    if (tid < 32) {
        float v = 0.f;
        #pragma unroll
        for (int s = 0; s < 16; s++) v += stats[s * 32 + tid];
        sums[tid] = v;
    }
    __syncthreads();
    if (tid < 16) {
        float cnt = 0.f;
        #pragma unroll
        for (int b = 0; b < NB; b++) cnt += (float)nvv[b];
        float mean = sums[tid] / cnt;
        float var  = fmaxf(sums[16 + tid] / cnt - mean * mean, 0.f);
        float scv = gamma[tid] * rsqrtf(var + EPSC);
        sbs[tid]      = scv;
        sbs[16 + tid] = beta[tid] - mean * scv;
    }
    __syncthreads();
}

// ---------------------------------------------------------------------------
// K5: BN1+ReLU on sorted bf16 -> sorted bf16; rows [cnt,NN) never read by
// conv2 -> no zero-fill; sentinel row NN still zeroed.
// ---------------------------------------------------------------------------
__global__ __launch_bounds__(256) void bnrelu_sorted_kernel(
    const unsigned short* __restrict__ in, const float* __restrict__ stats,
    const int* __restrict__ nvv,
    const float* __restrict__ gamma, const float* __restrict__ beta,
    unsigned short* __restrict__ outb)
{
    __shared__ float sbs[32];
    __shared__ float sums[32];
    compute_sb(stats, nvv, gamma, beta, sbs, sums);

    int b = blockIdx.y;
    int r = blockIdx.x * 256 + threadIdx.x;
    if (r > NN) return;
    int cnt = nvv[b];
    if (r >= cnt && r != NN) return;       // dead rows: never read downstream
    uint4 lo = make_uint4(0, 0, 0, 0), hi = lo;
    if (r < cnt) {
        const uint4* ip = (const uint4*)(in + ((size_t)b * NN + r) * 16);
        uint4 xl = ip[0], xh = ip[1];
        float y[16];
        #pragma unroll
        for (int c = 0; c < 16; c++) {
            unsigned u = (c < 8) ? ((const unsigned*)&xl)[c >> 1]
                                 : ((const unsigned*)&xh)[(c - 8) >> 1];
            unsigned short sv = (c & 1) ? (unsigned short)(u >> 16)
                                        : (unsigned short)(u & 0xffff);
            y[c] = fmaxf(fmaf(bf2f(sv), sbs[c], sbs[16 + c]), 0.f);
        }
        lo = make_uint4(pk2(y[0], y[1]), pk2(y[2], y[3]), pk2(y[4], y[5]), pk2(y[6], y[7]));
        hi = make_uint4(pk2(y[8], y[9]), pk2(y[10], y[11]), pk2(y[12], y[13]), pk2(y[14], y[15]));
    }
    unsigned short* op = outb + ((size_t)b * NS + r) * 16;
    *(uint4*)op       = lo;
    *(uint4*)(op + 8) = hi;
}

// ---------------------------------------------------------------------------
// K7: final BN2+ReLU, n-indexed: coalesced HBM writes, scattered L2/L3 reads.
// ---------------------------------------------------------------------------
__global__ __launch_bounds__(256) void final_out_kernel(
    const unsigned short* __restrict__ in,     // (B,NN,16) bf16 pre-BN sorted
    const int* __restrict__ rinv,              // (B,NN) n -> rank
    const float* __restrict__ stats, const int* __restrict__ nvv,
    const float* __restrict__ gamma, const float* __restrict__ beta,
    float* __restrict__ out)
{
    __shared__ float sbs[32];
    __shared__ float sums[32];
    compute_sb(stats, nvv, gamma, beta, sbs, sums);

    int b = blockIdx.y;
    int n = blockIdx.x * 256 + threadIdx.x;
    int cnt = nvv[b];
    float4* op = (float4*)(out + ((size_t)b * NN + n) * 16);
    if (n < cnt) {
        int r = rinv[(size_t)b * NN + n];
        const uint4* ip = (const uint4*)(in + ((size_t)b * NN + r) * 16);
        uint4 xl = ip[0], xh = ip[1];
        float y[16];
        #pragma unroll
        for (int c = 0; c < 16; c++) {
            unsigned u = (c < 8) ? ((const unsigned*)&xl)[c >> 1]
                                 : ((const unsigned*)&xh)[(c - 8) >> 1];
            unsigned short sv = (c & 1) ? (unsigned short)(u >> 16)
                                        : (unsigned short)(u & 0xffff);
            y[c] = fmaxf(fmaf(bf2f(sv), sbs[c], sbs[16 + c]), 0.f);
        }
        op[0] = make_float4(y[0],  y[1],  y[2],  y[3]);
        op[1] = make_float4(y[4],  y[5],  y[6],  y[7]);
        op[2] = make_float4(y[8],  y[9],  y[10], y[11]);
        op[3] = make_float4(y[12], y[13], y[14], y[15]);
    } else {
        float4 z = make_float4(0.f, 0.f, 0.f, 0.f);
        op[0] = z; op[1] = z; op[2] = z; op[3] = z;
    }
}

// ---------------------------------------------------------------------------
extern "C" void kernel_launch(void* const* d_in, const int* in_sizes, int n_in,
                              void* d_out, int out_size, void* d_ws, size_t ws_size,
                              hipStream_t stream)
{
    const float* feats  = (const float*)d_in[0];
    const int*   xyz    = (const int*)d_in[1];
    const int*   nvv    = (const int*)d_in[2];
    const float* w0     = (const float*)d_in[3];
    const float* w1     = (const float*)d_in[4];
    const float* nw0    = (const float*)d_in[5];
    const float* nw1    = (const float*)d_in[6];
    const float* gamma0 = (const float*)d_in[7];
    const float* beta0  = (const float*)d_in[8];
    const float* gamma1 = (const float*)d_in[9];
    const float* beta1  = (const float*)d_in[10];
    float* out = (float*)d_out;

    char* ws = (char*)d_ws;
    float*    stats1  = (float*)ws;          ws += 16 * 32 * 4;                // 2 KB (zeroed by K12)
    float*    stats2  = (float*)ws;          ws += 16 * 32 * 4;                // 2 KB (zeroed by K12)
    int2*     mwb     = (int2*)ws;           ws += (size_t)NB * NW * 8;        // 512 KB
    int2*     srow    = (int2*)ws;           ws += (size_t)NB * NN * 8;        // 4 MB
    unsigned short* sfA = (unsigned short*)ws; ws += (size_t)NB * NS * 16 * 2; // 16.8 MB
    unsigned short* sfB = (unsigned short*)ws; ws += (size_t)NB * NS * 16 * 2; // 16.8 MB
    unsigned short* bufPre = (unsigned short*)ws; ws += (size_t)NB * NN * 16 * 2; // 16 MB
    unsigned short* wfr = (unsigned short*)ws; ws += (size_t)2 * 14 * 512 * 2; // 28 KB
    int*      rinv    = (int*)ws;            ws += (size_t)NB * NN * 4;        // 2 MB

    // K12: mask(LDS)+scan+weight-pack+stats-zero (replaces memset+K1+K2)
    mask_scan_kernel<<<NB, 1024, 0, stream>>>(
        xyz, nvv, mwb, w0, w1, wfr, stats1, stats2);

    dim3 gridBN(NN / 256, NB);
    perm_gather_kernel<<<gridBN, 256, 0, stream>>>(xyz, nvv, mwb, feats, srow, sfA, rinv);

    // Layer 1: sorted bf16 in -> sorted bf16 (pre-BN) out + stats1
    conv_mfma_kernel<<<NBLKC, 256, 0, stream>>>(
        sfA, srow, nvv, mwb, wfr, nw0, bufPre, stats1);
    bnrelu_sorted_kernel<<<dim3(NN / 256 + 1, NB), 256, 0, stream>>>(
        bufPre, stats1, nvv, gamma0, beta0, sfB);

    // Layer 2: sorted bf16 in -> sorted bf16 (pre-BN) out + stats2
    conv_mfma_kernel<<<NBLKC, 256, 0, stream>>>(
        sfB, srow, nvv, mwb, wfr + 14 * 512, nw1, bufPre, stats2);

    // Final: BN2+ReLU, coalesced n-order writes, zero invalid rows
    final_out_kernel<<<dim3(NN / 256, NB), 256, 0, stream>>>(
        bufPre, rinv, stats2, nvv, gamma1, beta1, out);
}